// Round 8
// baseline (388.040 us; speedup 1.0000x reference)
//
#include <hip/hip_runtime.h>

// Sizes fixed by the reference: C=64, D=64 grid, ds grid 32^3.
#define GD 64
#define GDS 32

typedef _Float16 f16;
typedef __attribute__((ext_vector_type(8))) _Float16 f16x8;
typedef __attribute__((ext_vector_type(4))) float f32x4;

#define GLOAD_LDS16(SRC, DST)                                                        \
    __builtin_amdgcn_global_load_lds(                                                \
        (const __attribute__((address_space(1))) unsigned int*)(const void*)(SRC),   \
        (__attribute__((address_space(3))) unsigned int*)(void*)(DST), 16, 0, 0)

// ---------------------------------------------------------------------------
// init: idx_grid=-1, ds_mask=0, zrow=0 (zero 16B-source), feats1h zero row
__global__ __launch_bounds__(256) void init_kernel(int* __restrict__ idx_grid,
                                                   unsigned char* __restrict__ ds_mask,
                                                   f16* __restrict__ zrow,
                                                   f16* __restrict__ f1z) {
    int i = blockIdx.x * 256 + threadIdx.x;
    if (i < GD * GD * GD) idx_grid[i] = -1;
    if (i < GDS * GDS * GDS) ds_mask[i] = 0;
    if (i < 128) zrow[i] = (f16)0.f;
    if (i < 64) f1z[i] = (f16)0.f;
}

__global__ __launch_bounds__(256) void scatter_kernel(const int* __restrict__ coords, int N,
                                                      const int* __restrict__ coords_ds, int M,
                                                      int* __restrict__ idx_grid,
                                                      unsigned char* __restrict__ ds_mask) {
    int i = blockIdx.x * 256 + threadIdx.x;
    if (i < N) {
        int a = coords[i * 3], b = coords[i * 3 + 1], c = coords[i * 3 + 2];
        idx_grid[(a * GD + b) * GD + c] = i;
    }
    if (i < M) {
        int a = coords_ds[i * 3], b = coords_ds[i * 3 + 1], c = coords_ds[i * 3 + 2];
        ds_mask[(a * GDS + b) * GDS + c] = 1;
    }
}

// ---------------------------------------------------------------------------
// spatial sort via counting-compaction over idx_grid (262144 sites, 1024 chunks)
__global__ __launch_bounds__(256) void count_kernel(const int* __restrict__ idx_grid,
                                                    int* __restrict__ cnt) {
    __shared__ int c;
    if (threadIdx.x == 0) c = 0;
    __syncthreads();
    int s = blockIdx.x * 256 + threadIdx.x;
    bool act = idx_grid[s] >= 0;
    unsigned long long m = __ballot(act);
    if ((threadIdx.x & 63) == 0) atomicAdd(&c, __popcll(m));
    __syncthreads();
    if (threadIdx.x == 0) cnt[blockIdx.x] = c;
}

__global__ __launch_bounds__(1024) void prefix_kernel(const int* __restrict__ cnt,
                                                      int* __restrict__ off) {
    __shared__ int s[1024];
    int t = threadIdx.x;
    int v0 = cnt[t];
    s[t] = v0;
    __syncthreads();
    for (int d = 1; d < 1024; d <<= 1) {
        int v = 0;
        if (t >= d) v = s[t - d];
        __syncthreads();
        s[t] += v;
        __syncthreads();
    }
    off[t] = s[t] - v0;  // exclusive prefix
}

// emit sorted site list + perm; rewrite idx_grid[site] = sorted position q
__global__ __launch_bounds__(256) void emit_kernel(int* __restrict__ idx_grid,
                                                   const int* __restrict__ off,
                                                   int* __restrict__ sites,
                                                   int* __restrict__ perm) {
    int tid = threadIdx.x, bid = blockIdx.x;
    int s = bid * 256 + tid;
    int orig = idx_grid[s];
    bool act = orig >= 0;
    unsigned long long m = __ballot(act);
    int lane = tid & 63, wv = tid >> 6;
    __shared__ int wcnt[4];
    if (lane == 0) wcnt[wv] = __popcll(m);
    __syncthreads();
    int base = off[bid];
    for (int w = 0; w < wv; ++w) base += wcnt[w];
    int rank = __popcll(m & ((1ull << lane) - 1ull));
    if (act) {
        int q = base + rank;
        sites[q] = s;
        perm[q] = orig;
        idx_grid[s] = q;
    }
}

// ---------------------------------------------------------------------------
// pack all weights to f16 [tap][oc][ic] layouts (+ fused bias arrays, f32)
__global__ __launch_bounds__(256) void pack_kernel(
    const float* __restrict__ wf, const float* __restrict__ wd, const float* __restrict__ wc2,
    const float* __restrict__ wp00, const float* __restrict__ wp01, const float* __restrict__ wp10,
    const float* __restrict__ wp11, const float* __restrict__ wp12, const float* __restrict__ bp00,
    const float* __restrict__ bp01, const float* __restrict__ bp10, const float* __restrict__ bp11,
    int L, f16* __restrict__ wc1, f16* __restrict__ wdnh, f16* __restrict__ wc2h,
    f16* __restrict__ wfA, f16* __restrict__ wfB, f16* __restrict__ w12h, float* __restrict__ bA,
    float* __restrict__ bB) {
    int i = blockIdx.x * 256 + threadIdx.x;
    int n;
    n = 27 * 8192;
    if (i < n) {
        int tap = i >> 13, oc = (i >> 7) & 63, ic = i & 127;
        wc1[i] = (f16)wf[(tap * 128 + ic) * 64 + oc];
        return;
    }
    i -= n;
    n = 8 * 4096;
    if (i < n) {
        int t = i >> 12, oc = (i >> 6) & 63, ic = i & 63;
        wdnh[i] = (f16)wd[(t * 64 + ic) * 64 + oc];
        return;
    }
    i -= n;
    n = 27 * 4096;
    if (i < n) {
        int tap = i >> 12, oc = (i >> 6) & 63, ic = i & 63;
        wc2h[i] = (f16)wc2[(tap * 64 + ic) * 64 + oc];
        return;
    }
    i -= n;
    n = L * 27 * 2048;
    if (i < n) {  // wfA: [l][tap][oc(32)][ic(64)]; oc<16: w_p00, oc>=16: center-tap w_p10
        int l = i / (27 * 2048), r = i - l * 27 * 2048;
        int tap = r >> 11, oc = (r >> 6) & 31, ic = r & 63;
        float v = 0.f;
        if (oc < 16) v = wp00[(((size_t)l * 27 + tap) * 64 + ic) * 16 + oc];
        else if (tap == 13) v = wp10[((size_t)l * 64 + ic) * 16 + (oc - 16)];
        wfA[i] = (f16)v;
        return;
    }
    i -= n;
    n = L * 27 * 1536;
    if (i < n) {  // wfB: [l][tap][oc(48)][ic(32)]; oc<32: w_p01 (ic<16), oc>=32: w_p11 (ic>=16)
        int l = i / (27 * 1536), r = i - l * 27 * 1536;
        int tap = r / 1536, q = r - tap * 1536;
        int oc = q >> 5, ic = q & 31;
        float v = 0.f;
        if (oc < 32) {
            if (ic < 16) v = wp01[(((size_t)l * 27 + tap) * 16 + ic) * 32 + oc];
        } else {
            if (ic >= 16) v = wp11[(((size_t)l * 27 + tap) * 16 + (ic - 16)) * 16 + (oc - 32)];
        }
        wfB[i] = (f16)v;
        return;
    }
    i -= n;
    n = L * 512;
    if (i < n) {
        int l = i >> 9, q = i & 511, oc = q >> 4, ic = q & 15;
        w12h[i] = (f16)wp12[((size_t)l * 16 + ic) * 32 + oc];
        return;
    }
    i -= n;
    n = L * 32;
    if (i < n) {
        int l = i >> 5, oc = i & 31;
        bA[i] = (oc < 16) ? bp00[l * 16 + oc] : bp10[l * 16 + oc - 16];
        return;
    }
    i -= n;
    n = L * 48;
    if (i < n) {
        int l = i / 48, c = i - l * 48;
        bB[i] = (c < 32) ? bp01[l * 32 + c] : bp11[l * 16 + (c - 32)];
    }
}

// fuse fc1||fref into f16 rows [N+1][128] in SORTED order; row N = zeros
__global__ __launch_bounds__(256) void fusef_kernel(const float* __restrict__ fc1,
                                                    const float* __restrict__ fref,
                                                    const int* __restrict__ perm, int N,
                                                    f16* __restrict__ feats) {
    int i = blockIdx.x * 256 + threadIdx.x;
    if (i < (N + 1) * 128) {
        int q = i >> 7, c = i & 127;
        float v = 0.f;
        if (q < N) {
            int p = perm[q];
            v = (c < 64) ? fc1[p * 64 + c] : fref[p * 64 + c - 64];
        }
        feats[i] = (f16)v;
    }
}

// ---------------------------------------------------------------------------
// conv1: gather implicit-GEMM, counted-vmcnt TRIPLE-buffered pipeline, ONE
// barrier per tap. 64 sorted points x 64 oc per block, 4 waves (2m x 2n).
// Safety of single barrier: a wave passing barrier(t) has consumed (lgkmcnt-
// waited by compiler before MFMA use) all its ds_reads of buf((t-1)%3), so
// STAGE(t+2) into that buffer after barrier(t) cannot race.
// Full-perm XOR swizzle: c = cl ^ (row&15); row&15 == l16 on the read side so
// each 16-lane group hits 16 distinct 16B slots (conflict-free) and the read
// offsets are loop-invariant per thread.
__global__ __launch_bounds__(256) void conv1_pipe(const int* __restrict__ sites,
                                                  const int* __restrict__ idx_grid, int N,
                                                  const f16* __restrict__ featsB,  // (N+1)x128
                                                  const f16* __restrict__ wc1,     // 27x64x128
                                                  const float* __restrict__ bias,
                                                  f16* __restrict__ out /* (N+1) x 64 */) {
    __shared__ f16 xb[3][64 * 128];  // 3 x 16 KB
    __shared__ f16 wb[3][64 * 128];  // 3 x 16 KB
    __shared__ int nbr[64 * 27];
    const int tid = threadIdx.x;
    // bijective XCD-chunked swizzle: consecutive work chunks stay on one XCD
    const int nwg = gridDim.x, orig = blockIdx.x;
    const int qq = nwg >> 3, rr2 = nwg & 7;
    const int xcd = orig & 7, sub = orig >> 3;
    const int wg = (xcd < rr2 ? xcd * (qq + 1) : rr2 * (qq + 1) + (xcd - rr2) * qq) + sub;
    const int q0 = wg * 64;

    for (int t = tid; t < 64 * 27; t += 256) {
        int p = t / 27, tap = t - p * 27;
        int q = q0 + p, nb = N;
        if (q < N) {
            int s = sites[q];
            int i = (s >> 12) + tap / 9 - 1;
            int j = ((s >> 6) & 63) + (tap / 3) % 3 - 1;
            int k = (s & 63) + tap % 3 - 1;
            if ((unsigned)i < 64u && (unsigned)j < 64u && (unsigned)k < 64u) {
                int r = idx_grid[(i << 12) + (j << 6) + k];
                if (r >= 0) nb = r;
            }
        }
        nbr[t] = nb;
    }
    __syncthreads();

    const int lane = tid & 63, wid = tid >> 6;
    const int l16 = lane & 15, lq = lane >> 4;
    const int m0 = (wid >> 1) * 32, n0 = (wid & 1) * 32;

    // stage tap into buffer buf: X 1024 slots + W 1024 slots, 4+4 insts/thread.
    // LDS dest linear (wave-uniform base + lane*16); source pre-swizzled so a
    // read at logical chunk ch uses linear slot ch^(row&15) (rule #21).
    auto STAGE = [&](int tap, int buf) {
#pragma unroll
        for (int r = 0; r < 4; ++r) {
            int slot = r * 256 + tid;
            int row = slot >> 4, cl = slot & 15;
            int c = cl ^ (row & 15);
            const f16* src = featsB + (size_t)nbr[row * 27 + tap] * 128 + c * 8;
            GLOAD_LDS16(src, &xb[buf][0] + (size_t)(r * 256 + (tid & ~63)) * 8);
        }
#pragma unroll
        for (int r = 0; r < 4; ++r) {
            int slot = r * 256 + tid;
            int row = slot >> 4, cl = slot & 15;
            int c = cl ^ (row & 15);
            const f16* src = wc1 + (size_t)((tap * 64 + row) * 128 + c * 8);
            GLOAD_LDS16(src, &wb[buf][0] + (size_t)(r * 256 + (tid & ~63)) * 8);
        }
    };

    f32x4 acc[2][2] = {};
    STAGE(0, 0);
    STAGE(1, 1);
    int buf = 0;
    for (int tap = 0; tap < 27; ++tap) {
        // wait for THIS tap's 8 staging loads (next tap's 8 stay in flight)
        if (tap < 26) {
            asm volatile("s_waitcnt vmcnt(8)" ::: "memory");
        } else {
            asm volatile("s_waitcnt vmcnt(0)" ::: "memory");
        }
        __builtin_amdgcn_sched_barrier(0);
        __builtin_amdgcn_s_barrier();  // all waves' tap data visible
        // overlap: stage tap+2 into the buffer last read at tap-1 (free now)
        if (tap + 2 < 27) {
            int nb2 = buf + 2;
            if (nb2 >= 3) nb2 -= 3;
            STAGE(tap + 2, nb2);
        }

        const f16* xp = &xb[buf][0];
        const f16* wp = &wb[buf][0];
        f16x8 a[2][4], b[2][4];
#pragma unroll
        for (int mi = 0; mi < 2; ++mi) {
            int row = m0 + mi * 16 + l16;
#pragma unroll
            for (int ks = 0; ks < 4; ++ks)
                a[mi][ks] =
                    *(const f16x8*)(xp + (size_t)row * 128 + (size_t)((((ks * 4 + lq) ^ l16)) * 8));
        }
#pragma unroll
        for (int ni = 0; ni < 2; ++ni) {
            int col = n0 + ni * 16 + l16;
#pragma unroll
            for (int ks = 0; ks < 4; ++ks)
                b[ni][ks] =
                    *(const f16x8*)(wp + (size_t)col * 128 + (size_t)((((ks * 4 + lq) ^ l16)) * 8));
        }
#pragma unroll
        for (int mi = 0; mi < 2; ++mi)
#pragma unroll
            for (int ni = 0; ni < 2; ++ni)
#pragma unroll
                for (int ks = 0; ks < 4; ++ks)
                    acc[mi][ni] = __builtin_amdgcn_mfma_f32_16x16x32_f16(a[mi][ks], b[ni][ks],
                                                                         acc[mi][ni], 0, 0, 0);
        ++buf;
        if (buf >= 3) buf -= 3;
    }

#pragma unroll
    for (int ni = 0; ni < 2; ++ni) {
        int col = n0 + ni * 16 + l16;
        float bv = bias[col];
#pragma unroll
        for (int mi = 0; mi < 2; ++mi) {
#pragma unroll
            for (int j = 0; j < 4; ++j) {
                int q = q0 + m0 + mi * 16 + lq * 4 + j;
                if (q < N) {
                    float v = acc[mi][ni][j] + bv;
                    out[(size_t)q * 64 + col] = (f16)(v > 0.f ? v : 0.f);
                }
            }
        }
    }
}

// ---------------------------------------------------------------------------
// down: 2x2x2 stride-2, gather-MFMA. 128 ds-sites/block, 8 taps, dbuf staging.
__global__ __launch_bounds__(512) void down_mfma(const f16* __restrict__ feats1h, int N,
                                                 const int* __restrict__ idx_grid,
                                                 const f16* __restrict__ wdn,  // 8x64x64
                                                 const float* __restrict__ bias,
                                                 const unsigned char* __restrict__ mask,
                                                 f16* __restrict__ out /* 32768 x 64 */) {
    __shared__ f16 xs[2][128 * 64];
    __shared__ int nbr[128 * 8];
    const int tid = threadIdx.x;
    const int s0 = blockIdx.x * 128;
    for (int t = tid; t < 128 * 8; t += 512) {
        int sl = t >> 3, tp = t & 7;
        int s = s0 + sl;
        int i = s >> 10, j = (s >> 5) & 31, k = s & 31;
        int ci = 2 * i + (tp >> 2), cj = 2 * j + ((tp >> 1) & 1), ck = 2 * k + (tp & 1);
        int r = idx_grid[(ci * GD + cj) * GD + ck];
        nbr[t] = (r >= 0) ? r : N;
    }
    __syncthreads();
    auto stage = [&](int tp, int buf) {
#pragma unroll
        for (int rr = 0; rr < 2; ++rr) {
            int slot = rr * 512 + tid;
            int row = slot >> 3, cl = slot & 7;
            int c = cl ^ (row & 7);
            const f16* src = feats1h + (size_t)nbr[row * 8 + tp] * 64 + c * 8;
            f16* dst = &xs[buf][0] + (size_t)(rr * 512 + (tid & ~63)) * 8;
            GLOAD_LDS16(src, dst);
        }
    };
    const int lane = tid & 63, wid = tid >> 6;
    const int l16 = lane & 15, lq = lane >> 4;
    const int wm = wid >> 1, wn = wid & 1;
    const int m0 = wm * 32, n0 = wn * 32;
    f32x4 acc[2][2] = {};
    stage(0, 0);
    __syncthreads();
    for (int tp = 0; tp < 8; ++tp) {
        if (tp < 7) stage(tp + 1, (tp + 1) & 1);
        const f16* xb = &xs[tp & 1][0];
        f16x8 a[2][2], bfr[2][2];
#pragma unroll
        for (int mi = 0; mi < 2; ++mi) {
            int row = m0 + mi * 16 + l16;
#pragma unroll
            for (int ks = 0; ks < 2; ++ks) {
                int ch = ks * 4 + lq;
                a[mi][ks] = *(const f16x8*)(xb + (size_t)row * 64 + (ch ^ (row & 7)) * 8);
            }
        }
#pragma unroll
        for (int ni = 0; ni < 2; ++ni) {
            int col = n0 + ni * 16 + l16;
#pragma unroll
            for (int ks = 0; ks < 2; ++ks)
                bfr[ni][ks] =
                    *(const f16x8*)(wdn + (size_t)((tp * 64 + col) * 64 + (ks * 4 + lq) * 8));
        }
#pragma unroll
        for (int mi = 0; mi < 2; ++mi)
#pragma unroll
            for (int ni = 0; ni < 2; ++ni)
#pragma unroll
                for (int ks = 0; ks < 2; ++ks)
                    acc[mi][ni] = __builtin_amdgcn_mfma_f32_16x16x32_f16(a[mi][ks], bfr[ni][ks],
                                                                         acc[mi][ni], 0, 0, 0);
        __syncthreads();
    }
#pragma unroll
    for (int mi = 0; mi < 2; ++mi) {
        int m = m0 + mi * 16 + lq * 4;
        int site = s0 + m;
        unsigned mword = *(const unsigned*)(mask + site);
#pragma unroll
        for (int ni = 0; ni < 2; ++ni) {
            int col = n0 + ni * 16 + l16;
            float bv = bias[col];
#pragma unroll
            for (int j = 0; j < 4; ++j) {
                float v = 0.f;
                if ((mword >> (8 * j)) & 255) {
                    v = acc[mi][ni][j] + bv;
                    v = v > 0.f ? v : 0.f;
                }
                out[(size_t)(site + j) * 64 + col] = (f16)v;
            }
        }
    }
}

// ---------------------------------------------------------------------------
// Generic dense 32^3 masked conv (27 taps), f16 MFMA. Block = 128 sites
// (4 k-pencils at (i0, j0..j0+3)), 512 threads / 8 waves. Full halo (18
// pencils, k-padded, XOR-swizzled) staged ONCE in LDS; tap loop barrier-free;
// B-fragments direct from global (L2-resident). RELUFROM: relu for col>=RELUFROM.
// ostr: output row stride (allows padded layouts).
template <int CIN, int COUT, int NW, int RELUFROM>
__global__ __launch_bounds__(512) void dconv_kernel(const f16* __restrict__ x,
                                                    const f16* __restrict__ wp,  // 27 x COUT x CIN
                                                    const float* __restrict__ bias,
                                                    const unsigned char* __restrict__ mask,
                                                    const f16* __restrict__ zrow,
                                                    f16* __restrict__ out, int ostr) {
    constexpr int NCH = CIN / 8;          // 16B chunks per row
    constexpr int PSLOT = 34 * NCH;       // slots per pencil (k = -1..32)
    constexpr int STOT = 18 * PSLOT;      // total halo slots
    constexpr int RNDS = (STOT + 511) / 512;
    constexpr int MW = 8 / NW;
    constexpr int WM = 128 / MW, WN = COUT / NW;
    constexpr int FM = WM / 16, FN = WN / 16, KS = CIN / 32;
    __shared__ f16 xs[RNDS * 512 * 8];

    const int tid = threadIdx.x;
    const int bid = blockIdx.x;
    const int i0 = bid >> 3, j0 = (bid & 7) * 4;

    // stage halo: 18 pencils x 34 rows (pad rows & OOB pencils <- zrow)
    for (int rr = 0; rr < RNDS; ++rr) {
        int slot = rr * 512 + tid;
        int p = slot / PSLOT;
        int rem = slot - p * PSLOT;
        int r = rem / NCH;
        int cl = rem - r * NCH;
        int c = cl ^ (r & (NCH - 1));
        int gi = i0 + p / 6 - 1, gj = j0 + p % 6 - 1, gk = r - 1;
        bool ok = (slot < STOT) && ((unsigned)gi < 32u) && ((unsigned)gj < 32u) &&
                  ((unsigned)gk < 32u);
        const f16* src = ok ? (x + (size_t)(((gi * 32 + gj) * 32 + gk) * CIN + c * 8)) : zrow;
        f16* dst = xs + (size_t)(rr * 512 + (tid & ~63)) * 8;
        GLOAD_LDS16(src, dst);
    }
    __syncthreads();

    const int lane = tid & 63, wid = tid >> 6;
    const int l16 = lane & 15, lq = lane >> 4;
    const int wm = wid / NW, wn = wid - wm * NW;
    const int m0 = wm * WM, n0 = wn * WN;

    f32x4 acc[FM][FN] = {};

    for (int tap = 0; tap < 27; ++tap) {
        int di = tap / 9 - 1, dj = (tap / 3) % 3 - 1, dk = tap % 3 - 1;
        f16x8 a[FM][KS], bfr[FN][KS];
#pragma unroll
        for (int mi = 0; mi < FM; ++mi) {
            int m = m0 + mi * 16 + l16;
            int pj = m >> 5, k = m & 31;
            int p = (di + 1) * 6 + (pj + dj + 1);
            int r = k + dk + 1;
#pragma unroll
            for (int ks = 0; ks < KS; ++ks) {
                int ch = ks * 4 + lq;
                a[mi][ks] =
                    *(const f16x8*)(xs + (size_t)(p * PSLOT + r * NCH + (ch ^ (r & (NCH - 1)))) * 8);
            }
        }
#pragma unroll
        for (int ni = 0; ni < FN; ++ni) {
            int col = n0 + ni * 16 + l16;
#pragma unroll
            for (int ks = 0; ks < KS; ++ks)
                bfr[ni][ks] =
                    *(const f16x8*)(wp + (size_t)((tap * COUT + col) * CIN + (ks * 4 + lq) * 8));
        }
#pragma unroll
        for (int mi = 0; mi < FM; ++mi)
#pragma unroll
            for (int ni = 0; ni < FN; ++ni)
#pragma unroll
                for (int ks = 0; ks < KS; ++ks)
                    acc[mi][ni] = __builtin_amdgcn_mfma_f32_16x16x32_f16(a[mi][ks], bfr[ni][ks],
                                                                         acc[mi][ni], 0, 0, 0);
    }

#pragma unroll
    for (int mi = 0; mi < FM; ++mi) {
        int m = m0 + mi * 16 + lq * 4;
        int pj = m >> 5, k = m & 31;
        int gsite = ((i0 * 32) + (j0 + pj)) * 32 + k;
        unsigned mword = *(const unsigned*)(mask + gsite);
#pragma unroll
        for (int ni = 0; ni < FN; ++ni) {
            int col = n0 + ni * 16 + l16;
            float bv = bias[col];
#pragma unroll
            for (int j = 0; j < 4; ++j) {
                float v = 0.f;
                if ((mword >> (8 * j)) & 255) {
                    v = acc[mi][ni][j] + bv;
                    if (col >= RELUFROM) v = v > 0.f ? v : 0.f;
                }
                out[(size_t)(gsite + j) * ostr + col] = (f16)v;
            }
        }
    }
}

// ---------------------------------------------------------------------------
// tail: p1 = (u1 . w12 + b12)*mask; y = [p0 + x_lo | p1 + x_hi].
// Block = 64 sites x 4 waves; wave g (uniform role): g<2 add-path cols g*16..,
// g>=2 p1-matmul path oc (g-2)*16... ph stride 64 (padded) for 16B loads.
template <typename OUTT>
__global__ __launch_bounds__(256) void tail_kernel(const f16* __restrict__ ph,   // 32768 x 64(48)
                                                   const f16* __restrict__ xh,   // 32768 x 64
                                                   const f16* __restrict__ w12,  // 32 x 16
                                                   const float* __restrict__ b12,
                                                   const unsigned char* __restrict__ mask,
                                                   OUTT* __restrict__ y /* 32768 x 64 */) {
    __shared__ float ws[512];
    __shared__ float bs[32];
    int tid = threadIdx.x;
    ws[tid] = (float)w12[tid];
    ws[tid + 256] = (float)w12[tid + 256];
    if (tid < 32) bs[tid] = b12[tid];
    __syncthreads();
    int g = tid >> 6, lane = tid & 63;
    int site = blockIdx.x * 64 + lane;
    const f16x8* pr = (const f16x8*)(ph + (size_t)site * 64);
    const f16x8* xr = (const f16x8*)(xh + (size_t)site * 64);
    float yv[16];
    int col0;
    if (g < 2) {
        col0 = g * 16;
        f16x8 p0 = pr[g * 2], p1 = pr[g * 2 + 1];
        f16x8 x0 = xr[g * 2], x1 = xr[g * 2 + 1];
#pragma unroll
        for (int j = 0; j < 8; ++j) {
            yv[j] = (float)p0[j] + (float)x0[j];
            yv[8 + j] = (float)p1[j] + (float)x1[j];
        }
    } else {
        int oc0 = (g - 2) * 16;
        col0 = 32 + oc0;
        f16x8 u0 = pr[4], u1 = pr[5];
        float u[16];
#pragma unroll
        for (int j = 0; j < 8; ++j) {
            u[j] = (float)u0[j];
            u[8 + j] = (float)u1[j];
        }
        f16x8 x0 = xr[4 + (g - 2) * 2], x1 = xr[5 + (g - 2) * 2];
        bool mk = mask[site] != 0;
#pragma unroll
        for (int oc = 0; oc < 16; ++oc) {
            float s = 0.f;
#pragma unroll
            for (int ic = 0; ic < 16; ++ic) s += u[ic] * ws[(oc0 + oc) * 16 + ic];
            float p1v = mk ? (s + bs[oc0 + oc]) : 0.f;
            yv[oc] = p1v + (float)((oc < 8) ? x0[oc] : x1[oc - 8]);
        }
    }
#pragma unroll
    for (int j = 0; j < 16; ++j) y[(size_t)site * 64 + col0 + j] = (OUTT)yv[j];
}

// final gather: out[m][oc] = xF[ds_site(m)][oc]
__global__ __launch_bounds__(256) void gather_kernel(const float* __restrict__ x,
                                                     const int* __restrict__ coords_ds, int M,
                                                     float* __restrict__ out) {
    int i = blockIdx.x * 256 + threadIdx.x;
    if (i < M * 64) {
        int m = i >> 6, oc = i & 63;
        int a = coords_ds[m * 3], b = coords_ds[m * 3 + 1], c = coords_ds[m * 3 + 2];
        out[i] = x[((size_t)((a * GDS + b) * GDS + c) << 6) + oc];
    }
}

// ---------------------------------------------------------------------------
extern "C" void kernel_launch(void* const* d_in, const int* in_sizes, int n_in,
                              void* d_out, int out_size, void* d_ws, size_t ws_size,
                              hipStream_t stream) {
    const int* coords = (const int*)d_in[0];
    const int* coords_ds = (const int*)d_in[1];
    const float* fc1 = (const float*)d_in[2];
    const float* fref = (const float*)d_in[3];
    const float* w_fuse = (const float*)d_in[4];
    const float* b_fuse = (const float*)d_in[5];
    const float* w_down = (const float*)d_in[6];
    const float* b_down = (const float*)d_in[7];
    const float* w_conv2 = (const float*)d_in[8];
    const float* b_conv2 = (const float*)d_in[9];
    const float* w_p00 = (const float*)d_in[10];
    const float* b_p00 = (const float*)d_in[11];
    const float* w_p01 = (const float*)d_in[12];
    const float* b_p01 = (const float*)d_in[13];
    const float* w_p10 = (const float*)d_in[14];
    const float* b_p10 = (const float*)d_in[15];
    const float* w_p11 = (const float*)d_in[16];
    const float* b_p11 = (const float*)d_in[17];
    const float* w_p12 = (const float*)d_in[18];
    const float* b_p12 = (const float*)d_in[19];

    const int N = in_sizes[0] / 3;
    const int M = in_sizes[1] / 3;
    const int L = in_sizes[10] / (27 * 64 * 16);
    const int NSITES = GDS * GDS * GDS;  // 32768

    size_t off = 0;
    auto alloc = [&](size_t bytes) {
        void* p = (char*)d_ws + off;
        off += (bytes + 255) & ~(size_t)255;
        return p;
    };
    int* idx_grid = (int*)alloc((size_t)GD * GD * GD * 4);
    unsigned char* ds_mask = (unsigned char*)alloc(NSITES);
    f16* zrow = (f16*)alloc(256);
    int* chunk_cnt = (int*)alloc(1024 * 4);
    int* chunk_off = (int*)alloc(1024 * 4);
    int* sites = (int*)alloc((size_t)N * 4);
    int* perm = (int*)alloc((size_t)N * 4);
    f16* featsB = (f16*)alloc((size_t)(N + 1) * 128 * 2);
    f16* feats1h = (f16*)alloc((size_t)(N + 1) * 64 * 2);
    f16* xdown = (f16*)alloc((size_t)NSITES * 64 * 2);
    f16* x0 = (f16*)alloc((size_t)NSITES * 64 * 2);
    f16* y1 = (f16*)alloc((size_t)NSITES * 64 * 2);
    f16* y2 = (f16*)alloc((size_t)NSITES * 64 * 2);
    f16* thh = (f16*)alloc((size_t)NSITES * 32 * 2);
    f16* ph = (f16*)alloc((size_t)NSITES * 64 * 2);  // stride 64, 48 used
    float* xF = (float*)alloc((size_t)NSITES * 64 * 4);
    f16* wc1 = (f16*)alloc((size_t)27 * 8192 * 2);
    f16* wdnh = (f16*)alloc((size_t)8 * 4096 * 2);
    f16* wc2h = (f16*)alloc((size_t)27 * 4096 * 2);
    f16* wfA = (f16*)alloc((size_t)L * 27 * 2048 * 2);
    f16* wfB = (f16*)alloc((size_t)L * 27 * 1536 * 2);
    f16* w12h = (f16*)alloc((size_t)L * 512 * 2);
    float* bA = (float*)alloc((size_t)L * 32 * 4);
    float* bB = (float*)alloc((size_t)L * 48 * 4);
    (void)ws_size;

    float* out = (float*)d_out;
    (void)out_size;
    (void)n_in;

    init_kernel<<<(GD * GD * GD + 255) / 256, 256, 0, stream>>>(idx_grid, ds_mask, zrow,
                                                                feats1h + (size_t)N * 64);
    {
        int mx = N > M ? N : M;
        scatter_kernel<<<(mx + 255) / 256, 256, 0, stream>>>(coords, N, coords_ds, M, idx_grid,
                                                             ds_mask);
    }
    // spatial sort of points (compaction over idx_grid)
    count_kernel<<<1024, 256, 0, stream>>>(idx_grid, chunk_cnt);
    prefix_kernel<<<1, 1024, 0, stream>>>(chunk_cnt, chunk_off);
    emit_kernel<<<1024, 256, 0, stream>>>(idx_grid, chunk_off, sites, perm);
    {
        int tot = 27 * 8192 + 8 * 4096 + 27 * 4096 + L * 27 * 2048 + L * 27 * 1536 + L * 512 +
                  L * 32 + L * 48;
        pack_kernel<<<(tot + 255) / 256, 256, 0, stream>>>(
            w_fuse, w_down, w_conv2, w_p00, w_p01, w_p10, w_p11, w_p12, b_p00, b_p01, b_p10, b_p11,
            L, wc1, wdnh, wc2h, wfA, wfB, w12h, bA, bB);
    }
    fusef_kernel<<<((N + 1) * 128 + 255) / 256, 256, 0, stream>>>(fc1, fref, perm, N, featsB);

    conv1_pipe<<<(N + 63) / 64, 256, 0, stream>>>(sites, idx_grid, N, featsB, wc1, b_fuse,
                                                  feats1h);
    down_mfma<<<NSITES / 128, 512, 0, stream>>>(feats1h, N, idx_grid, wdnh, b_down, ds_mask,
                                                xdown);
    dconv_kernel<64, 64, 2, 64>
        <<<256, 512, 0, stream>>>(xdown, wc2h, b_conv2, ds_mask, zrow, x0, 64);

    f16* x = x0;
    for (int l = 0; l < L; ++l) {
        dconv_kernel<64, 32, 2, 0>
            <<<256, 512, 0, stream>>>(x, wfA + (size_t)l * 27 * 2048, bA + l * 32, ds_mask, zrow,
                                      thh, 32);
        dconv_kernel<32, 48, 1, 32>
            <<<256, 512, 0, stream>>>(thh, wfB + (size_t)l * 27 * 1536, bB + l * 48, ds_mask, zrow,
                                      ph, 64);
        if (l < L - 1) {
            f16* yn = (l == 0) ? y1 : y2;
            tail_kernel<f16><<<NSITES / 64, 256, 0, stream>>>(ph, x, w12h + (size_t)l * 512,
                                                              b_p12 + l * 32, ds_mask, yn);
            x = yn;
        } else {
            tail_kernel<float><<<NSITES / 64, 256, 0, stream>>>(ph, x, w12h + (size_t)l * 512,
                                                                b_p12 + l * 32, ds_mask, xF);
        }
    }

    gather_kernel<<<(M * 64 + 255) / 256, 256, 0, stream>>>(xF, coords_ds, M, out);
}

// Round 9
// 292.278 us; speedup vs baseline: 1.3276x; 1.3276x over previous
//
#include <hip/hip_runtime.h>

// Sizes fixed by the reference: C=64, D=64 grid, ds grid 32^3.
#define GD 64
#define GDS 32

typedef _Float16 f16;
typedef __attribute__((ext_vector_type(8))) _Float16 f16x8;
typedef __attribute__((ext_vector_type(4))) float f32x4;

#define GLOAD_LDS16(SRC, DST)                                                        \
    __builtin_amdgcn_global_load_lds(                                                \
        (const __attribute__((address_space(1))) unsigned int*)(const void*)(SRC),   \
        (__attribute__((address_space(3))) unsigned int*)(void*)(DST), 16, 0, 0)

// ---------------------------------------------------------------------------
// init: idx_grid=-1, ds_mask=0, zrow=0 (zero 16B-source), feats1h zero row
__global__ __launch_bounds__(256) void init_kernel(int* __restrict__ idx_grid,
                                                   unsigned char* __restrict__ ds_mask,
                                                   f16* __restrict__ zrow,
                                                   f16* __restrict__ f1z) {
    int i = blockIdx.x * 256 + threadIdx.x;
    if (i < GD * GD * GD) idx_grid[i] = -1;
    if (i < GDS * GDS * GDS) ds_mask[i] = 0;
    if (i < 128) zrow[i] = (f16)0.f;
    if (i < 64) f1z[i] = (f16)0.f;
}

__global__ __launch_bounds__(256) void scatter_kernel(const int* __restrict__ coords, int N,
                                                      const int* __restrict__ coords_ds, int M,
                                                      int* __restrict__ idx_grid,
                                                      unsigned char* __restrict__ ds_mask) {
    int i = blockIdx.x * 256 + threadIdx.x;
    if (i < N) {
        int a = coords[i * 3], b = coords[i * 3 + 1], c = coords[i * 3 + 2];
        idx_grid[(a * GD + b) * GD + c] = i;
    }
    if (i < M) {
        int a = coords_ds[i * 3], b = coords_ds[i * 3 + 1], c = coords_ds[i * 3 + 2];
        ds_mask[(a * GDS + b) * GDS + c] = 1;
    }
}

// ---------------------------------------------------------------------------
// spatial sort via counting-compaction over idx_grid (262144 sites, 1024 chunks)
__global__ __launch_bounds__(256) void count_kernel(const int* __restrict__ idx_grid,
                                                    int* __restrict__ cnt) {
    __shared__ int c;
    if (threadIdx.x == 0) c = 0;
    __syncthreads();
    int s = blockIdx.x * 256 + threadIdx.x;
    bool act = idx_grid[s] >= 0;
    unsigned long long m = __ballot(act);
    if ((threadIdx.x & 63) == 0) atomicAdd(&c, __popcll(m));
    __syncthreads();
    if (threadIdx.x == 0) cnt[blockIdx.x] = c;
}

__global__ __launch_bounds__(1024) void prefix_kernel(const int* __restrict__ cnt,
                                                      int* __restrict__ off) {
    __shared__ int s[1024];
    int t = threadIdx.x;
    int v0 = cnt[t];
    s[t] = v0;
    __syncthreads();
    for (int d = 1; d < 1024; d <<= 1) {
        int v = 0;
        if (t >= d) v = s[t - d];
        __syncthreads();
        s[t] += v;
        __syncthreads();
    }
    off[t] = s[t] - v0;  // exclusive prefix
}

// emit sorted site list + perm; rewrite idx_grid[site] = sorted position q
__global__ __launch_bounds__(256) void emit_kernel(int* __restrict__ idx_grid,
                                                   const int* __restrict__ off,
                                                   int* __restrict__ sites,
                                                   int* __restrict__ perm) {
    int tid = threadIdx.x, bid = blockIdx.x;
    int s = bid * 256 + tid;
    int orig = idx_grid[s];
    bool act = orig >= 0;
    unsigned long long m = __ballot(act);
    int lane = tid & 63, wv = tid >> 6;
    __shared__ int wcnt[4];
    if (lane == 0) wcnt[wv] = __popcll(m);
    __syncthreads();
    int base = off[bid];
    for (int w = 0; w < wv; ++w) base += wcnt[w];
    int rank = __popcll(m & ((1ull << lane) - 1ull));
    if (act) {
        int q = base + rank;
        sites[q] = s;
        perm[q] = orig;
        idx_grid[s] = q;
    }
}

// ---------------------------------------------------------------------------
// pack all weights to f16 [tap][oc][ic] layouts (+ fused bias arrays, f32)
__global__ __launch_bounds__(256) void pack_kernel(
    const float* __restrict__ wf, const float* __restrict__ wd, const float* __restrict__ wc2,
    const float* __restrict__ wp00, const float* __restrict__ wp01, const float* __restrict__ wp10,
    const float* __restrict__ wp11, const float* __restrict__ wp12, const float* __restrict__ bp00,
    const float* __restrict__ bp01, const float* __restrict__ bp10, const float* __restrict__ bp11,
    int L, f16* __restrict__ wc1, f16* __restrict__ wdnh, f16* __restrict__ wc2h,
    f16* __restrict__ wfA, f16* __restrict__ wfB, f16* __restrict__ w12h, float* __restrict__ bA,
    float* __restrict__ bB) {
    int i = blockIdx.x * 256 + threadIdx.x;
    int n;
    n = 27 * 8192;
    if (i < n) {
        int tap = i >> 13, oc = (i >> 7) & 63, ic = i & 127;
        wc1[i] = (f16)wf[(tap * 128 + ic) * 64 + oc];
        return;
    }
    i -= n;
    n = 8 * 4096;
    if (i < n) {
        int t = i >> 12, oc = (i >> 6) & 63, ic = i & 63;
        wdnh[i] = (f16)wd[(t * 64 + ic) * 64 + oc];
        return;
    }
    i -= n;
    n = 27 * 4096;
    if (i < n) {
        int tap = i >> 12, oc = (i >> 6) & 63, ic = i & 63;
        wc2h[i] = (f16)wc2[(tap * 64 + ic) * 64 + oc];
        return;
    }
    i -= n;
    n = L * 27 * 2048;
    if (i < n) {  // wfA: [l][tap][oc(32)][ic(64)]; oc<16: w_p00, oc>=16: center-tap w_p10
        int l = i / (27 * 2048), r = i - l * 27 * 2048;
        int tap = r >> 11, oc = (r >> 6) & 31, ic = r & 63;
        float v = 0.f;
        if (oc < 16) v = wp00[(((size_t)l * 27 + tap) * 64 + ic) * 16 + oc];
        else if (tap == 13) v = wp10[((size_t)l * 64 + ic) * 16 + (oc - 16)];
        wfA[i] = (f16)v;
        return;
    }
    i -= n;
    n = L * 27 * 1536;
    if (i < n) {  // wfB: [l][tap][oc(48)][ic(32)]; oc<32: w_p01 (ic<16), oc>=32: w_p11 (ic>=16)
        int l = i / (27 * 1536), r = i - l * 27 * 1536;
        int tap = r / 1536, q = r - tap * 1536;
        int oc = q >> 5, ic = q & 31;
        float v = 0.f;
        if (oc < 32) {
            if (ic < 16) v = wp01[(((size_t)l * 27 + tap) * 16 + ic) * 32 + oc];
        } else {
            if (ic >= 16) v = wp11[(((size_t)l * 27 + tap) * 16 + (ic - 16)) * 16 + (oc - 32)];
        }
        wfB[i] = (f16)v;
        return;
    }
    i -= n;
    n = L * 512;
    if (i < n) {
        int l = i >> 9, q = i & 511, oc = q >> 4, ic = q & 15;
        w12h[i] = (f16)wp12[((size_t)l * 16 + ic) * 32 + oc];
        return;
    }
    i -= n;
    n = L * 32;
    if (i < n) {
        int l = i >> 5, oc = i & 31;
        bA[i] = (oc < 16) ? bp00[l * 16 + oc] : bp10[l * 16 + oc - 16];
        return;
    }
    i -= n;
    n = L * 48;
    if (i < n) {
        int l = i / 48, c = i - l * 48;
        bB[i] = (c < 32) ? bp01[l * 32 + c] : bp11[l * 16 + (c - 32)];
    }
}

// fuse fc1||fref into f16 rows [N+1][128] in SORTED order; row N = zeros
__global__ __launch_bounds__(256) void fusef_kernel(const float* __restrict__ fc1,
                                                    const float* __restrict__ fref,
                                                    const int* __restrict__ perm, int N,
                                                    f16* __restrict__ feats) {
    int i = blockIdx.x * 256 + threadIdx.x;
    if (i < (N + 1) * 128) {
        int q = i >> 7, c = i & 127;
        float v = 0.f;
        if (q < N) {
            int p = perm[q];
            v = (c < 64) ? fc1[p * 64 + c] : fref[p * 64 + c - 64];
        }
        feats[i] = (f16)v;
    }
}

// ---------------------------------------------------------------------------
// conv1: gather implicit-GEMM, counted-vmcnt DOUBLE-buffered pipeline (round-7
// structure, 72KB LDS -> 2 blocks/CU) + round-8 full-perm conflict-free
// swizzle (c = cl ^ (row&15); read slot = ch ^ l16, loop-invariant per lane).
__global__ __launch_bounds__(256) void conv1_pipe(const int* __restrict__ sites,
                                                  const int* __restrict__ idx_grid, int N,
                                                  const f16* __restrict__ featsB,  // (N+1)x128
                                                  const f16* __restrict__ wc1,     // 27x64x128
                                                  const float* __restrict__ bias,
                                                  f16* __restrict__ out /* (N+1) x 64 */) {
    __shared__ f16 xb[2][64 * 128];  // 2 x 16 KB
    __shared__ f16 wb[2][64 * 128];  // 2 x 16 KB
    __shared__ int nbr[64 * 27];
    const int tid = threadIdx.x;
    // bijective XCD-chunked swizzle: consecutive work chunks stay on one XCD
    const int nwg = gridDim.x, orig = blockIdx.x;
    const int qq = nwg >> 3, rr2 = nwg & 7;
    const int xcd = orig & 7, sub = orig >> 3;
    const int wg = (xcd < rr2 ? xcd * (qq + 1) : rr2 * (qq + 1) + (xcd - rr2) * qq) + sub;
    const int q0 = wg * 64;

    for (int t = tid; t < 64 * 27; t += 256) {
        int p = t / 27, tap = t - p * 27;
        int q = q0 + p, nb = N;
        if (q < N) {
            int s = sites[q];
            int i = (s >> 12) + tap / 9 - 1;
            int j = ((s >> 6) & 63) + (tap / 3) % 3 - 1;
            int k = (s & 63) + tap % 3 - 1;
            if ((unsigned)i < 64u && (unsigned)j < 64u && (unsigned)k < 64u) {
                int r = idx_grid[(i << 12) + (j << 6) + k];
                if (r >= 0) nb = r;
            }
        }
        nbr[t] = nb;
    }
    __syncthreads();

    const int lane = tid & 63, wid = tid >> 6;
    const int l16 = lane & 15, lq = lane >> 4;
    const int m0 = (wid >> 1) * 32, n0 = (wid & 1) * 32;

    auto STAGE = [&](int tap, int buf) {
#pragma unroll
        for (int r = 0; r < 4; ++r) {
            int slot = r * 256 + tid;
            int row = slot >> 4, cl = slot & 15;
            int c = cl ^ (row & 15);
            const f16* src = featsB + (size_t)nbr[row * 27 + tap] * 128 + c * 8;
            GLOAD_LDS16(src, &xb[buf][0] + (size_t)(r * 256 + (tid & ~63)) * 8);
        }
#pragma unroll
        for (int r = 0; r < 4; ++r) {
            int slot = r * 256 + tid;
            int row = slot >> 4, cl = slot & 15;
            int c = cl ^ (row & 15);
            const f16* src = wc1 + (size_t)((tap * 64 + row) * 128 + c * 8);
            GLOAD_LDS16(src, &wb[buf][0] + (size_t)(r * 256 + (tid & ~63)) * 8);
        }
    };

    f32x4 acc[2][2] = {};
    STAGE(0, 0);
    STAGE(1, 1);
    for (int tap = 0; tap < 27; ++tap) {
        // wait for THIS tap's 8 staging loads (next tap's 8 stay in flight)
        if (tap < 26) {
            asm volatile("s_waitcnt vmcnt(8)" ::: "memory");
        } else {
            asm volatile("s_waitcnt vmcnt(0)" ::: "memory");
        }
        __builtin_amdgcn_sched_barrier(0);
        __builtin_amdgcn_s_barrier();  // all waves' tap data visible

        const f16* xp = &xb[tap & 1][0];
        const f16* wp = &wb[tap & 1][0];
        f16x8 a[2][4], b[2][4];
#pragma unroll
        for (int mi = 0; mi < 2; ++mi) {
            int row = m0 + mi * 16 + l16;
#pragma unroll
            for (int ks = 0; ks < 4; ++ks)
                a[mi][ks] =
                    *(const f16x8*)(xp + (size_t)row * 128 + (size_t)((((ks * 4 + lq) ^ l16)) * 8));
        }
#pragma unroll
        for (int ni = 0; ni < 2; ++ni) {
            int col = n0 + ni * 16 + l16;
#pragma unroll
            for (int ks = 0; ks < 4; ++ks)
                b[ni][ks] =
                    *(const f16x8*)(wp + (size_t)col * 128 + (size_t)((((ks * 4 + lq) ^ l16)) * 8));
        }
#pragma unroll
        for (int mi = 0; mi < 2; ++mi)
#pragma unroll
            for (int ni = 0; ni < 2; ++ni)
#pragma unroll
                for (int ks = 0; ks < 4; ++ks)
                    acc[mi][ni] = __builtin_amdgcn_mfma_f32_16x16x32_f16(a[mi][ks], b[ni][ks],
                                                                         acc[mi][ni], 0, 0, 0);
        // this wave's ds_reads done before any wave overwrites the buffer
        asm volatile("s_waitcnt lgkmcnt(0)" ::: "memory");
        __builtin_amdgcn_sched_barrier(0);
        __builtin_amdgcn_s_barrier();
        if (tap + 2 < 27) STAGE(tap + 2, tap & 1);
    }

#pragma unroll
    for (int ni = 0; ni < 2; ++ni) {
        int col = n0 + ni * 16 + l16;
        float bv = bias[col];
#pragma unroll
        for (int mi = 0; mi < 2; ++mi) {
#pragma unroll
            for (int j = 0; j < 4; ++j) {
                int q = q0 + m0 + mi * 16 + lq * 4 + j;
                if (q < N) {
                    float v = acc[mi][ni][j] + bv;
                    out[(size_t)q * 64 + col] = (f16)(v > 0.f ? v : 0.f);
                }
            }
        }
    }
}

// ---------------------------------------------------------------------------
// down: 2x2x2 stride-2, gather-MFMA, counted-vmcnt pipeline for X AND W
// (W was read direct from global in-loop -> compiler-sunk latency).
__global__ __launch_bounds__(512) void down_mfma(const f16* __restrict__ feats1h, int N,
                                                 const int* __restrict__ idx_grid,
                                                 const f16* __restrict__ wdn,  // 8x64x64
                                                 const float* __restrict__ bias,
                                                 const unsigned char* __restrict__ mask,
                                                 f16* __restrict__ out /* 32768 x 64 */) {
    __shared__ f16 xs[2][128 * 64];
    __shared__ f16 wl[2][512 * 8];
    __shared__ int nbr[128 * 8];
    const int tid = threadIdx.x;
    const int s0 = blockIdx.x * 128;
    for (int t = tid; t < 128 * 8; t += 512) {
        int sl = t >> 3, tp = t & 7;
        int s = s0 + sl;
        int i = s >> 10, j = (s >> 5) & 31, k = s & 31;
        int ci = 2 * i + (tp >> 2), cj = 2 * j + ((tp >> 1) & 1), ck = 2 * k + (tp & 1);
        int r = idx_grid[(ci * GD + cj) * GD + ck];
        nbr[t] = (r >= 0) ? r : N;
    }
    __syncthreads();
    auto STAGEX = [&](int tp, int buf) {
#pragma unroll
        for (int rr = 0; rr < 2; ++rr) {
            int slot = rr * 512 + tid;
            int row = slot >> 3, cl = slot & 7;
            int c = cl ^ (row & 7);
            const f16* src = feats1h + (size_t)nbr[row * 8 + tp] * 64 + c * 8;
            GLOAD_LDS16(src, &xs[buf][0] + (size_t)(rr * 512 + (tid & ~63)) * 8);
        }
    };
    auto STAGEW = [&](int tp, int buf) {
        int row = tid >> 3, cl = tid & 7;
        int c = cl ^ (row & 7);
        const f16* src = wdn + (size_t)((tp * 64 + row) * 64 + c * 8);
        GLOAD_LDS16(src, &wl[buf][0] + (size_t)(tid & ~63) * 8);
    };
    const int lane = tid & 63, wid = tid >> 6;
    const int l16 = lane & 15, lq = lane >> 4;
    const int wm = wid >> 1, wn = wid & 1;
    const int m0 = wm * 32, n0 = wn * 32;
    f32x4 acc[2][2] = {};
    STAGEX(0, 0);
    STAGEW(0, 0);
    STAGEX(1, 1);
    STAGEW(1, 1);
    for (int tp = 0; tp < 8; ++tp) {
        if (tp < 7) {
            asm volatile("s_waitcnt vmcnt(3)" ::: "memory");
        } else {
            asm volatile("s_waitcnt vmcnt(0)" ::: "memory");
        }
        __builtin_amdgcn_sched_barrier(0);
        __builtin_amdgcn_s_barrier();
        const f16* xbp = &xs[tp & 1][0];
        const f16* wbp = &wl[tp & 1][0];
        f16x8 a[2][2], bfr[2][2];
#pragma unroll
        for (int mi = 0; mi < 2; ++mi) {
            int row = m0 + mi * 16 + l16;
#pragma unroll
            for (int ks = 0; ks < 2; ++ks) {
                int ch = ks * 4 + lq;
                a[mi][ks] = *(const f16x8*)(xbp + (size_t)row * 64 + (ch ^ (row & 7)) * 8);
            }
        }
#pragma unroll
        for (int ni = 0; ni < 2; ++ni) {
            int col = n0 + ni * 16 + l16;
#pragma unroll
            for (int ks = 0; ks < 2; ++ks) {
                int ch = ks * 4 + lq;
                bfr[ni][ks] = *(const f16x8*)(wbp + (size_t)col * 64 + (ch ^ (col & 7)) * 8);
            }
        }
#pragma unroll
        for (int mi = 0; mi < 2; ++mi)
#pragma unroll
            for (int ni = 0; ni < 2; ++ni)
#pragma unroll
                for (int ks = 0; ks < 2; ++ks)
                    acc[mi][ni] = __builtin_amdgcn_mfma_f32_16x16x32_f16(a[mi][ks], bfr[ni][ks],
                                                                         acc[mi][ni], 0, 0, 0);
        asm volatile("s_waitcnt lgkmcnt(0)" ::: "memory");
        __builtin_amdgcn_sched_barrier(0);
        __builtin_amdgcn_s_barrier();
        if (tp + 2 < 8) {
            STAGEX(tp + 2, tp & 1);
            STAGEW(tp + 2, tp & 1);
        }
    }
#pragma unroll
    for (int mi = 0; mi < 2; ++mi) {
        int m = m0 + mi * 16 + lq * 4;
        int site = s0 + m;
        unsigned mword = *(const unsigned*)(mask + site);
#pragma unroll
        for (int ni = 0; ni < 2; ++ni) {
            int col = n0 + ni * 16 + l16;
            float bv = bias[col];
#pragma unroll
            for (int j = 0; j < 4; ++j) {
                float v = 0.f;
                if ((mword >> (8 * j)) & 255) {
                    v = acc[mi][ni][j] + bv;
                    v = v > 0.f ? v : 0.f;
                }
                out[(size_t)(site + j) * 64 + col] = (f16)v;
            }
        }
    }
}

// ---------------------------------------------------------------------------
// Generic dense 32^3 masked conv (27 taps), f16 MFMA. Halo staged once in LDS
// (unchanged); NEW: W double-buffered via counted-vmcnt pipeline (was direct
// global reads in-loop -> compiler-sunk L2 latency per tap).
template <int CIN, int COUT, int NW, int RELUFROM>
__global__ __launch_bounds__(512) void dconv_kernel(const f16* __restrict__ x,
                                                    const f16* __restrict__ wp,  // 27 x COUT x CIN
                                                    const float* __restrict__ bias,
                                                    const unsigned char* __restrict__ mask,
                                                    const f16* __restrict__ zrow,
                                                    f16* __restrict__ out, int ostr) {
    constexpr int NCH = CIN / 8;          // 16B chunks per row
    constexpr int PSLOT = 34 * NCH;       // slots per pencil (k = -1..32)
    constexpr int STOT = 18 * PSLOT;      // total halo slots
    constexpr int RNDS = (STOT + 511) / 512;
    constexpr int MW = 8 / NW;
    constexpr int WM = 128 / MW, WN = COUT / NW;
    constexpr int FM = WM / 16, FN = WN / 16, KS = CIN / 32;
    constexpr int WSLOTS = COUT * NCH;  // real W slots per tap (<=512)
    __shared__ f16 xs[RNDS * 512 * 8];
    __shared__ f16 wl[2][512 * 8];

    const int tid = threadIdx.x;
    const int bid = blockIdx.x;
    const int i0 = bid >> 3, j0 = (bid & 7) * 4;

    // stage halo: 18 pencils x 34 rows (pad rows & OOB pencils <- zrow)
    for (int rr = 0; rr < RNDS; ++rr) {
        int slot = rr * 512 + tid;
        int p = slot / PSLOT;
        int rem = slot - p * PSLOT;
        int r = rem / NCH;
        int cl = rem - r * NCH;
        int c = cl ^ (r & (NCH - 1));
        int gi = i0 + p / 6 - 1, gj = j0 + p % 6 - 1, gk = r - 1;
        bool ok = (slot < STOT) && ((unsigned)gi < 32u) && ((unsigned)gj < 32u) &&
                  ((unsigned)gk < 32u);
        const f16* src = ok ? (x + (size_t)(((gi * 32 + gj) * 32 + gk) * CIN + c * 8)) : zrow;
        f16* dst = xs + (size_t)(rr * 512 + (tid & ~63)) * 8;
        GLOAD_LDS16(src, dst);
    }
    // W stage: 1 inst/thread (pad slots >= WSLOTS load wp base, keeps per-wave
    // vmcnt uniform)
    auto STAGEW = [&](int tap, int buf) {
        int row = tid / NCH, cl = tid % NCH;
        int c = cl ^ (row & (NCH - 1));
        const f16* src = (tid < WSLOTS) ? (wp + (size_t)((tap * COUT + row) * CIN + c * 8)) : wp;
        GLOAD_LDS16(src, &wl[buf][0] + (size_t)(tid & ~63) * 8);
    };
    STAGEW(0, 0);
    STAGEW(1, 1);

    const int lane = tid & 63, wid = tid >> 6;
    const int l16 = lane & 15, lq = lane >> 4;
    const int wm = wid / NW, wn = wid - wm * NW;
    const int m0 = wm * WM, n0 = wn * WN;

    f32x4 acc[FM][FN] = {};

    for (int tap = 0; tap < 27; ++tap) {
        // wait halo + W(tap); W(tap+1)'s single inst stays in flight
        if (tap < 26) {
            asm volatile("s_waitcnt vmcnt(1)" ::: "memory");
        } else {
            asm volatile("s_waitcnt vmcnt(0)" ::: "memory");
        }
        __builtin_amdgcn_sched_barrier(0);
        __builtin_amdgcn_s_barrier();

        int di = tap / 9 - 1, dj = (tap / 3) % 3 - 1, dk = tap % 3 - 1;
        const f16* wbp = &wl[tap & 1][0];
        f16x8 a[FM][KS], bfr[FN][KS];
#pragma unroll
        for (int mi = 0; mi < FM; ++mi) {
            int m = m0 + mi * 16 + l16;
            int pj = m >> 5, k = m & 31;
            int p = (di + 1) * 6 + (pj + dj + 1);
            int r = k + dk + 1;
#pragma unroll
            for (int ks = 0; ks < KS; ++ks) {
                int ch = ks * 4 + lq;
                a[mi][ks] =
                    *(const f16x8*)(xs + (size_t)(p * PSLOT + r * NCH + (ch ^ (r & (NCH - 1)))) * 8);
            }
        }
#pragma unroll
        for (int ni = 0; ni < FN; ++ni) {
            int col = n0 + ni * 16 + l16;
#pragma unroll
            for (int ks = 0; ks < KS; ++ks) {
                int ch = ks * 4 + lq;
                bfr[ni][ks] =
                    *(const f16x8*)(wbp + (size_t)(col * NCH + (ch ^ (col & (NCH - 1)))) * 8);
            }
        }
#pragma unroll
        for (int mi = 0; mi < FM; ++mi)
#pragma unroll
            for (int ni = 0; ni < FN; ++ni)
#pragma unroll
                for (int ks = 0; ks < KS; ++ks)
                    acc[mi][ni] = __builtin_amdgcn_mfma_f32_16x16x32_f16(a[mi][ks], bfr[ni][ks],
                                                                         acc[mi][ni], 0, 0, 0);
        asm volatile("s_waitcnt lgkmcnt(0)" ::: "memory");
        __builtin_amdgcn_sched_barrier(0);
        __builtin_amdgcn_s_barrier();
        if (tap + 2 < 27) STAGEW(tap + 2, tap & 1);
    }

#pragma unroll
    for (int mi = 0; mi < FM; ++mi) {
        int m = m0 + mi * 16 + lq * 4;
        int pj = m >> 5, k = m & 31;
        int gsite = ((i0 * 32) + (j0 + pj)) * 32 + k;
        unsigned mword = *(const unsigned*)(mask + gsite);
#pragma unroll
        for (int ni = 0; ni < FN; ++ni) {
            int col = n0 + ni * 16 + l16;
            float bv = bias[col];
#pragma unroll
            for (int j = 0; j < 4; ++j) {
                float v = 0.f;
                if ((mword >> (8 * j)) & 255) {
                    v = acc[mi][ni][j] + bv;
                    if (col >= RELUFROM) v = v > 0.f ? v : 0.f;
                }
                out[(size_t)(gsite + j) * ostr + col] = (f16)v;
            }
        }
    }
}

// ---------------------------------------------------------------------------
// tail: p1 = (u1 . w12 + b12)*mask; y = [p0 + x_lo | p1 + x_hi].
// Block = 64 sites x 4 waves; wave g (uniform role): g<2 add-path cols g*16..,
// g>=2 p1-matmul path oc (g-2)*16... ph stride 64 (padded) for 16B loads.
template <typename OUTT>
__global__ __launch_bounds__(256) void tail_kernel(const f16* __restrict__ ph,   // 32768 x 64(48)
                                                   const f16* __restrict__ xh,   // 32768 x 64
                                                   const f16* __restrict__ w12,  // 32 x 16
                                                   const float* __restrict__ b12,
                                                   const unsigned char* __restrict__ mask,
                                                   OUTT* __restrict__ y /* 32768 x 64 */) {
    __shared__ float ws[512];
    __shared__ float bs[32];
    int tid = threadIdx.x;
    ws[tid] = (float)w12[tid];
    ws[tid + 256] = (float)w12[tid + 256];
    if (tid < 32) bs[tid] = b12[tid];
    __syncthreads();
    int g = tid >> 6, lane = tid & 63;
    int site = blockIdx.x * 64 + lane;
    const f16x8* pr = (const f16x8*)(ph + (size_t)site * 64);
    const f16x8* xr = (const f16x8*)(xh + (size_t)site * 64);
    float yv[16];
    int col0;
    if (g < 2) {
        col0 = g * 16;
        f16x8 p0 = pr[g * 2], p1 = pr[g * 2 + 1];
        f16x8 x0 = xr[g * 2], x1 = xr[g * 2 + 1];
#pragma unroll
        for (int j = 0; j < 8; ++j) {
            yv[j] = (float)p0[j] + (float)x0[j];
            yv[8 + j] = (float)p1[j] + (float)x1[j];
        }
    } else {
        int oc0 = (g - 2) * 16;
        col0 = 32 + oc0;
        f16x8 u0 = pr[4], u1 = pr[5];
        float u[16];
#pragma unroll
        for (int j = 0; j < 8; ++j) {
            u[j] = (float)u0[j];
            u[8 + j] = (float)u1[j];
        }
        f16x8 x0 = xr[4 + (g - 2) * 2], x1 = xr[5 + (g - 2) * 2];
        bool mk = mask[site] != 0;
#pragma unroll
        for (int oc = 0; oc < 16; ++oc) {
            float s = 0.f;
#pragma unroll
            for (int ic = 0; ic < 16; ++ic) s += u[ic] * ws[(oc0 + oc) * 16 + ic];
            float p1v = mk ? (s + bs[oc0 + oc]) : 0.f;
            yv[oc] = p1v + (float)((oc < 8) ? x0[oc] : x1[oc - 8]);
        }
    }
#pragma unroll
    for (int j = 0; j < 16; ++j) y[(size_t)site * 64 + col0 + j] = (OUTT)yv[j];
}

// final gather: out[m][oc] = xF[ds_site(m)][oc]
__global__ __launch_bounds__(256) void gather_kernel(const float* __restrict__ x,
                                                     const int* __restrict__ coords_ds, int M,
                                                     float* __restrict__ out) {
    int i = blockIdx.x * 256 + threadIdx.x;
    if (i < M * 64) {
        int m = i >> 6, oc = i & 63;
        int a = coords_ds[m * 3], b = coords_ds[m * 3 + 1], c = coords_ds[m * 3 + 2];
        out[i] = x[((size_t)((a * GDS + b) * GDS + c) << 6) + oc];
    }
}

// ---------------------------------------------------------------------------
extern "C" void kernel_launch(void* const* d_in, const int* in_sizes, int n_in,
                              void* d_out, int out_size, void* d_ws, size_t ws_size,
                              hipStream_t stream) {
    const int* coords = (const int*)d_in[0];
    const int* coords_ds = (const int*)d_in[1];
    const float* fc1 = (const float*)d_in[2];
    const float* fref = (const float*)d_in[3];
    const float* w_fuse = (const float*)d_in[4];
    const float* b_fuse = (const float*)d_in[5];
    const float* w_down = (const float*)d_in[6];
    const float* b_down = (const float*)d_in[7];
    const float* w_conv2 = (const float*)d_in[8];
    const float* b_conv2 = (const float*)d_in[9];
    const float* w_p00 = (const float*)d_in[10];
    const float* b_p00 = (const float*)d_in[11];
    const float* w_p01 = (const float*)d_in[12];
    const float* b_p01 = (const float*)d_in[13];
    const float* w_p10 = (const float*)d_in[14];
    const float* b_p10 = (const float*)d_in[15];
    const float* w_p11 = (const float*)d_in[16];
    const float* b_p11 = (const float*)d_in[17];
    const float* w_p12 = (const float*)d_in[18];
    const float* b_p12 = (const float*)d_in[19];

    const int N = in_sizes[0] / 3;
    const int M = in_sizes[1] / 3;
    const int L = in_sizes[10] / (27 * 64 * 16);
    const int NSITES = GDS * GDS * GDS;  // 32768

    size_t off = 0;
    auto alloc = [&](size_t bytes) {
        void* p = (char*)d_ws + off;
        off += (bytes + 255) & ~(size_t)255;
        return p;
    };
    int* idx_grid = (int*)alloc((size_t)GD * GD * GD * 4);
    unsigned char* ds_mask = (unsigned char*)alloc(NSITES);
    f16* zrow = (f16*)alloc(256);
    int* chunk_cnt = (int*)alloc(1024 * 4);
    int* chunk_off = (int*)alloc(1024 * 4);
    int* sites = (int*)alloc((size_t)N * 4);
    int* perm = (int*)alloc((size_t)N * 4);
    f16* featsB = (f16*)alloc((size_t)(N + 1) * 128 * 2);
    f16* feats1h = (f16*)alloc((size_t)(N + 1) * 64 * 2);
    f16* xdown = (f16*)alloc((size_t)NSITES * 64 * 2);
    f16* x0 = (f16*)alloc((size_t)NSITES * 64 * 2);
    f16* y1 = (f16*)alloc((size_t)NSITES * 64 * 2);
    f16* y2 = (f16*)alloc((size_t)NSITES * 64 * 2);
    f16* thh = (f16*)alloc((size_t)NSITES * 32 * 2);
    f16* ph = (f16*)alloc((size_t)NSITES * 64 * 2);  // stride 64, 48 used
    float* xF = (float*)alloc((size_t)NSITES * 64 * 4);
    f16* wc1 = (f16*)alloc((size_t)27 * 8192 * 2);
    f16* wdnh = (f16*)alloc((size_t)8 * 4096 * 2);
    f16* wc2h = (f16*)alloc((size_t)27 * 4096 * 2);
    f16* wfA = (f16*)alloc((size_t)L * 27 * 2048 * 2);
    f16* wfB = (f16*)alloc((size_t)L * 27 * 1536 * 2);
    f16* w12h = (f16*)alloc((size_t)L * 512 * 2);
    float* bA = (float*)alloc((size_t)L * 32 * 4);
    float* bB = (float*)alloc((size_t)L * 48 * 4);
    (void)ws_size;

    float* out = (float*)d_out;
    (void)out_size;
    (void)n_in;

    init_kernel<<<(GD * GD * GD + 255) / 256, 256, 0, stream>>>(idx_grid, ds_mask, zrow,
                                                                feats1h + (size_t)N * 64);
    {
        int mx = N > M ? N : M;
        scatter_kernel<<<(mx + 255) / 256, 256, 0, stream>>>(coords, N, coords_ds, M, idx_grid,
                                                             ds_mask);
    }
    // spatial sort of points (compaction over idx_grid)
    count_kernel<<<1024, 256, 0, stream>>>(idx_grid, chunk_cnt);
    prefix_kernel<<<1, 1024, 0, stream>>>(chunk_cnt, chunk_off);
    emit_kernel<<<1024, 256, 0, stream>>>(idx_grid, chunk_off, sites, perm);
    {
        int tot = 27 * 8192 + 8 * 4096 + 27 * 4096 + L * 27 * 2048 + L * 27 * 1536 + L * 512 +
                  L * 32 + L * 48;
        pack_kernel<<<(tot + 255) / 256, 256, 0, stream>>>(
            w_fuse, w_down, w_conv2, w_p00, w_p01, w_p10, w_p11, w_p12, b_p00, b_p01, b_p10, b_p11,
            L, wc1, wdnh, wc2h, wfA, wfB, w12h, bA, bB);
    }
    fusef_kernel<<<((N + 1) * 128 + 255) / 256, 256, 0, stream>>>(fc1, fref, perm, N, featsB);

    conv1_pipe<<<(N + 63) / 64, 256, 0, stream>>>(sites, idx_grid, N, featsB, wc1, b_fuse,
                                                  feats1h);
    down_mfma<<<NSITES / 128, 512, 0, stream>>>(feats1h, N, idx_grid, wdnh, b_down, ds_mask,
                                                xdown);
    dconv_kernel<64, 64, 2, 64>
        <<<256, 512, 0, stream>>>(xdown, wc2h, b_conv2, ds_mask, zrow, x0, 64);

    f16* x = x0;
    for (int l = 0; l < L; ++l) {
        dconv_kernel<64, 32, 2, 0>
            <<<256, 512, 0, stream>>>(x, wfA + (size_t)l * 27 * 2048, bA + l * 32, ds_mask, zrow,
                                      thh, 32);
        dconv_kernel<32, 48, 1, 32>
            <<<256, 512, 0, stream>>>(thh, wfB + (size_t)l * 27 * 1536, bB + l * 48, ds_mask, zrow,
                                      ph, 64);
        if (l < L - 1) {
            f16* yn = (l == 0) ? y1 : y2;
            tail_kernel<f16><<<NSITES / 64, 256, 0, stream>>>(ph, x, w12h + (size_t)l * 512,
                                                              b_p12 + l * 32, ds_mask, yn);
            x = yn;
        } else {
            tail_kernel<float><<<NSITES / 64, 256, 0, stream>>>(ph, x, w12h + (size_t)l * 512,
                                                                b_p12 + l * 32, ds_mask, xF);
        }
    }

    gather_kernel<<<(M * 64 + 255) / 256, 256, 0, stream>>>(xF, coords_ds, M, out);
}

// Round 10
// 274.324 us; speedup vs baseline: 1.4145x; 1.0654x over previous
//
#include <hip/hip_runtime.h>

// Sizes fixed by the reference: C=64, D=64 grid, ds grid 32^3.
#define GD 64
#define GDS 32

typedef _Float16 f16;
typedef __attribute__((ext_vector_type(8))) _Float16 f16x8;
typedef __attribute__((ext_vector_type(4))) float f32x4;

#define GLOAD_LDS16(SRC, DST)                                                        \
    __builtin_amdgcn_global_load_lds(                                                \
        (const __attribute__((address_space(1))) unsigned int*)(const void*)(SRC),   \
        (__attribute__((address_space(3))) unsigned int*)(void*)(DST), 16, 0, 0)

// ---------------------------------------------------------------------------
// fused init + weight-pack: init idx_grid=-1, ds_mask=0, zrow=0, feats1h zero
// row; pack all weights to f16 [tap][oc][ic] (+ fused bias arrays). All
// branches are independent writes; thread i does the init job AND the pack job
// for index i.
__global__ __launch_bounds__(256) void init_pack_kernel(
    int* __restrict__ idx_grid, unsigned char* __restrict__ ds_mask, f16* __restrict__ zrow,
    f16* __restrict__ f1z, const float* __restrict__ wf, const float* __restrict__ wd,
    const float* __restrict__ wc2, const float* __restrict__ wp00, const float* __restrict__ wp01,
    const float* __restrict__ wp10, const float* __restrict__ wp11, const float* __restrict__ wp12,
    const float* __restrict__ bp00, const float* __restrict__ bp01, const float* __restrict__ bp10,
    const float* __restrict__ bp11, int L, f16* __restrict__ wc1, f16* __restrict__ wdnh,
    f16* __restrict__ wc2h, f16* __restrict__ wfA, f16* __restrict__ wfB, f16* __restrict__ w12h,
    float* __restrict__ bA, float* __restrict__ bB) {
    int i0 = blockIdx.x * 256 + threadIdx.x;
    if (i0 < GD * GD * GD) idx_grid[i0] = -1;
    if (i0 < GDS * GDS * GDS) ds_mask[i0] = 0;
    if (i0 < 128) zrow[i0] = (f16)0.f;
    if (i0 < 64) f1z[i0] = (f16)0.f;

    int i = i0;
    int n;
    n = 27 * 8192;
    if (i < n) {
        int tap = i >> 13, oc = (i >> 7) & 63, ic = i & 127;
        wc1[i] = (f16)wf[(tap * 128 + ic) * 64 + oc];
        return;
    }
    i -= n;
    n = 8 * 4096;
    if (i < n) {
        int t = i >> 12, oc = (i >> 6) & 63, ic = i & 63;
        wdnh[i] = (f16)wd[(t * 64 + ic) * 64 + oc];
        return;
    }
    i -= n;
    n = 27 * 4096;
    if (i < n) {
        int tap = i >> 12, oc = (i >> 6) & 63, ic = i & 63;
        wc2h[i] = (f16)wc2[(tap * 64 + ic) * 64 + oc];
        return;
    }
    i -= n;
    n = L * 27 * 2048;
    if (i < n) {  // wfA: [l][tap][oc(32)][ic(64)]; oc<16: w_p00, oc>=16: center-tap w_p10
        int l = i / (27 * 2048), r = i - l * 27 * 2048;
        int tap = r >> 11, oc = (r >> 6) & 31, ic = r & 63;
        float v = 0.f;
        if (oc < 16) v = wp00[(((size_t)l * 27 + tap) * 64 + ic) * 16 + oc];
        else if (tap == 13) v = wp10[((size_t)l * 64 + ic) * 16 + (oc - 16)];
        wfA[i] = (f16)v;
        return;
    }
    i -= n;
    n = L * 27 * 1536;
    if (i < n) {  // wfB: [l][tap][oc(48)][ic(32)]; oc<32: w_p01 (ic<16), oc>=32: w_p11 (ic>=16)
        int l = i / (27 * 1536), r = i - l * 27 * 1536;
        int tap = r / 1536, q = r - tap * 1536;
        int oc = q >> 5, ic = q & 31;
        float v = 0.f;
        if (oc < 32) {
            if (ic < 16) v = wp01[(((size_t)l * 27 + tap) * 16 + ic) * 32 + oc];
        } else {
            if (ic >= 16) v = wp11[(((size_t)l * 27 + tap) * 16 + (ic - 16)) * 16 + (oc - 32)];
        }
        wfB[i] = (f16)v;
        return;
    }
    i -= n;
    n = L * 512;
    if (i < n) {
        int l = i >> 9, q = i & 511, oc = q >> 4, ic = q & 15;
        w12h[i] = (f16)wp12[((size_t)l * 16 + ic) * 32 + oc];
        return;
    }
    i -= n;
    n = L * 32;
    if (i < n) {
        int l = i >> 5, oc = i & 31;
        bA[i] = (oc < 16) ? bp00[l * 16 + oc] : bp10[l * 16 + oc - 16];
        return;
    }
    i -= n;
    n = L * 48;
    if (i < n) {
        int l = i / 48, c = i - l * 48;
        bB[i] = (c < 32) ? bp01[l * 32 + c] : bp11[l * 16 + (c - 32)];
    }
}

__global__ __launch_bounds__(256) void scatter_kernel(const int* __restrict__ coords, int N,
                                                      const int* __restrict__ coords_ds, int M,
                                                      int* __restrict__ idx_grid,
                                                      unsigned char* __restrict__ ds_mask) {
    int i = blockIdx.x * 256 + threadIdx.x;
    if (i < N) {
        int a = coords[i * 3], b = coords[i * 3 + 1], c = coords[i * 3 + 2];
        idx_grid[(a * GD + b) * GD + c] = i;
    }
    if (i < M) {
        int a = coords_ds[i * 3], b = coords_ds[i * 3 + 1], c = coords_ds[i * 3 + 2];
        ds_mask[(a * GDS + b) * GDS + c] = 1;
    }
}

// ---------------------------------------------------------------------------
// spatial sort via counting-compaction over idx_grid (262144 sites, 1024 chunks)
__global__ __launch_bounds__(256) void count_kernel(const int* __restrict__ idx_grid,
                                                    int* __restrict__ cnt) {
    __shared__ int c;
    if (threadIdx.x == 0) c = 0;
    __syncthreads();
    int s = blockIdx.x * 256 + threadIdx.x;
    bool act = idx_grid[s] >= 0;
    unsigned long long m = __ballot(act);
    if ((threadIdx.x & 63) == 0) atomicAdd(&c, __popcll(m));
    __syncthreads();
    if (threadIdx.x == 0) cnt[blockIdx.x] = c;
}

__global__ __launch_bounds__(1024) void prefix_kernel(const int* __restrict__ cnt,
                                                      int* __restrict__ off) {
    __shared__ int s[1024];
    int t = threadIdx.x;
    int v0 = cnt[t];
    s[t] = v0;
    __syncthreads();
    for (int d = 1; d < 1024; d <<= 1) {
        int v = 0;
        if (t >= d) v = s[t - d];
        __syncthreads();
        s[t] += v;
        __syncthreads();
    }
    off[t] = s[t] - v0;  // exclusive prefix
}

// emit sorted site list + perm; rewrite idx_grid[site] = sorted position q
__global__ __launch_bounds__(256) void emit_kernel(int* __restrict__ idx_grid,
                                                   const int* __restrict__ off,
                                                   int* __restrict__ sites,
                                                   int* __restrict__ perm) {
    int tid = threadIdx.x, bid = blockIdx.x;
    int s = bid * 256 + tid;
    int orig = idx_grid[s];
    bool act = orig >= 0;
    unsigned long long m = __ballot(act);
    int lane = tid & 63, wv = tid >> 6;
    __shared__ int wcnt[4];
    if (lane == 0) wcnt[wv] = __popcll(m);
    __syncthreads();
    int base = off[bid];
    for (int w = 0; w < wv; ++w) base += wcnt[w];
    int rank = __popcll(m & ((1ull << lane) - 1ull));
    if (act) {
        int q = base + rank;
        sites[q] = s;
        perm[q] = orig;
        idx_grid[s] = q;
    }
}

// fuse fc1||fref into f16 rows [N+1][128] in SORTED order; row N = zeros
__global__ __launch_bounds__(256) void fusef_kernel(const float* __restrict__ fc1,
                                                    const float* __restrict__ fref,
                                                    const int* __restrict__ perm, int N,
                                                    f16* __restrict__ feats) {
    int i = blockIdx.x * 256 + threadIdx.x;
    if (i < (N + 1) * 128) {
        int q = i >> 7, c = i & 127;
        float v = 0.f;
        if (q < N) {
            int p = perm[q];
            v = (c < 64) ? fc1[p * 64 + c] : fref[p * 64 + c - 64];
        }
        feats[i] = (f16)v;
    }
}

// ---------------------------------------------------------------------------
// conv1: gather implicit-GEMM, counted-vmcnt double-buffered pipeline, 2-way
// tap-parity SPLIT-K. 512 threads / 8 waves; wave-group grp = wid>>2 computes
// taps with tap&1==grp (14/13 taps); all waves co-stage into shared buffers
// (4 insts/thread -> vmcnt(4)). 16 waves/CU (2 blocks) double the latency-
// hiding pool vs the 4-wave version. Cross-group K-reduction via one-time LDS
// bounce (f32, stride-65, overlaid on xb after the loop).
__global__ __launch_bounds__(512) void conv1_pipe(const int* __restrict__ sites,
                                                  const int* __restrict__ idx_grid, int N,
                                                  const f16* __restrict__ featsB,  // (N+1)x128
                                                  const f16* __restrict__ wc1,     // 27x64x128
                                                  const float* __restrict__ bias,
                                                  f16* __restrict__ out /* (N+1) x 64 */) {
    __shared__ f16 xb[2][64 * 128];  // 2 x 16 KB (also reduction scratch after loop)
    __shared__ f16 wb[2][64 * 128];  // 2 x 16 KB
    __shared__ int nbr[64 * 27];
    const int tid = threadIdx.x;
    // bijective XCD-chunked swizzle: consecutive work chunks stay on one XCD
    const int nwg = gridDim.x, orig = blockIdx.x;
    const int qq = nwg >> 3, rr2 = nwg & 7;
    const int xcd = orig & 7, sub = orig >> 3;
    const int wg = (xcd < rr2 ? xcd * (qq + 1) : rr2 * (qq + 1) + (xcd - rr2) * qq) + sub;
    const int q0 = wg * 64;

    for (int t = tid; t < 64 * 27; t += 512) {
        int p = t / 27, tap = t - p * 27;
        int q = q0 + p, nb = N;
        if (q < N) {
            int s = sites[q];
            int i = (s >> 12) + tap / 9 - 1;
            int j = ((s >> 6) & 63) + (tap / 3) % 3 - 1;
            int k = (s & 63) + tap % 3 - 1;
            if ((unsigned)i < 64u && (unsigned)j < 64u && (unsigned)k < 64u) {
                int r = idx_grid[(i << 12) + (j << 6) + k];
                if (r >= 0) nb = r;
            }
        }
        nbr[t] = nb;
    }
    __syncthreads();

    const int lane = tid & 63, wid = tid >> 6;
    const int l16 = lane & 15, lq = lane >> 4;
    const int grp = wid >> 2, w4 = wid & 3;
    const int m0 = (w4 >> 1) * 32, n0 = (w4 & 1) * 32;

    // stage tap: X 1024 slots + W 1024 slots over 512 threads = 2+2 insts.
    auto STAGE = [&](int tap, int buf) {
#pragma unroll
        for (int r = 0; r < 2; ++r) {
            int slot = r * 512 + tid;
            int row = slot >> 4, cl = slot & 15;
            int c = cl ^ (row & 15);
            const f16* src = featsB + (size_t)nbr[row * 27 + tap] * 128 + c * 8;
            GLOAD_LDS16(src, &xb[buf][0] + (size_t)(r * 512 + (tid & ~63)) * 8);
        }
#pragma unroll
        for (int r = 0; r < 2; ++r) {
            int slot = r * 512 + tid;
            int row = slot >> 4, cl = slot & 15;
            int c = cl ^ (row & 15);
            const f16* src = wc1 + (size_t)((tap * 64 + row) * 128 + c * 8);
            GLOAD_LDS16(src, &wb[buf][0] + (size_t)(r * 512 + (tid & ~63)) * 8);
        }
    };

    f32x4 acc[2][2] = {};
    STAGE(0, 0);
    STAGE(1, 1);
    for (int tap = 0; tap < 27; ++tap) {
        // wait for THIS tap's 4 staging loads (next tap's 4 stay in flight)
        if (tap < 26) {
            asm volatile("s_waitcnt vmcnt(4)" ::: "memory");
        } else {
            asm volatile("s_waitcnt vmcnt(0)" ::: "memory");
        }
        __builtin_amdgcn_sched_barrier(0);
        __builtin_amdgcn_s_barrier();  // all waves' tap data visible

        if (grp == (tap & 1)) {
            const f16* xp = &xb[tap & 1][0];
            const f16* wp = &wb[tap & 1][0];
            f16x8 a[2][4], b[2][4];
#pragma unroll
            for (int mi = 0; mi < 2; ++mi) {
                int row = m0 + mi * 16 + l16;
#pragma unroll
                for (int ks = 0; ks < 4; ++ks)
                    a[mi][ks] = *(const f16x8*)(xp + (size_t)row * 128 +
                                                (size_t)((((ks * 4 + lq) ^ l16)) * 8));
            }
#pragma unroll
            for (int ni = 0; ni < 2; ++ni) {
                int col = n0 + ni * 16 + l16;
#pragma unroll
                for (int ks = 0; ks < 4; ++ks)
                    b[ni][ks] = *(const f16x8*)(wp + (size_t)col * 128 +
                                                (size_t)((((ks * 4 + lq) ^ l16)) * 8));
            }
#pragma unroll
            for (int mi = 0; mi < 2; ++mi)
#pragma unroll
                for (int ni = 0; ni < 2; ++ni)
#pragma unroll
                    for (int ks = 0; ks < 4; ++ks)
                        acc[mi][ni] = __builtin_amdgcn_mfma_f32_16x16x32_f16(a[mi][ks], b[ni][ks],
                                                                             acc[mi][ni], 0, 0, 0);
        }
        // this wave's ds_reads done before any wave overwrites the buffer
        asm volatile("s_waitcnt lgkmcnt(0)" ::: "memory");
        __builtin_amdgcn_sched_barrier(0);
        __builtin_amdgcn_s_barrier();
        if (tap + 2 < 27) STAGE(tap + 2, tap & 1);
    }

    // cross-group K-reduction: group 1 -> LDS (f32, stride 65), group 0 adds.
    float* red = (float*)&xb[0][0];  // 64*65*4 = 16.6KB < 32KB of xb
    if (grp == 1) {
#pragma unroll
        for (int mi = 0; mi < 2; ++mi)
#pragma unroll
            for (int ni = 0; ni < 2; ++ni)
#pragma unroll
                for (int j = 0; j < 4; ++j)
                    red[(m0 + mi * 16 + lq * 4 + j) * 65 + n0 + ni * 16 + l16] = acc[mi][ni][j];
    }
    __syncthreads();
    if (grp == 0) {
#pragma unroll
        for (int ni = 0; ni < 2; ++ni) {
            int col = n0 + ni * 16 + l16;
            float bv = bias[col];
#pragma unroll
            for (int mi = 0; mi < 2; ++mi) {
#pragma unroll
                for (int j = 0; j < 4; ++j) {
                    int row = m0 + mi * 16 + lq * 4 + j;
                    int q = q0 + row;
                    if (q < N) {
                        float v = acc[mi][ni][j] + red[row * 65 + col] + bv;
                        out[(size_t)q * 64 + col] = (f16)(v > 0.f ? v : 0.f);
                    }
                }
            }
        }
    }
}

// ---------------------------------------------------------------------------
// down: 2x2x2 stride-2, gather-MFMA, counted-vmcnt pipeline for X AND W.
__global__ __launch_bounds__(512) void down_mfma(const f16* __restrict__ feats1h, int N,
                                                 const int* __restrict__ idx_grid,
                                                 const f16* __restrict__ wdn,  // 8x64x64
                                                 const float* __restrict__ bias,
                                                 const unsigned char* __restrict__ mask,
                                                 f16* __restrict__ out /* 32768 x 64 */) {
    __shared__ f16 xs[2][128 * 64];
    __shared__ f16 wl[2][512 * 8];
    __shared__ int nbr[128 * 8];
    const int tid = threadIdx.x;
    const int s0 = blockIdx.x * 128;
    for (int t = tid; t < 128 * 8; t += 512) {
        int sl = t >> 3, tp = t & 7;
        int s = s0 + sl;
        int i = s >> 10, j = (s >> 5) & 31, k = s & 31;
        int ci = 2 * i + (tp >> 2), cj = 2 * j + ((tp >> 1) & 1), ck = 2 * k + (tp & 1);
        int r = idx_grid[(ci * GD + cj) * GD + ck];
        nbr[t] = (r >= 0) ? r : N;
    }
    __syncthreads();
    auto STAGEX = [&](int tp, int buf) {
#pragma unroll
        for (int rr = 0; rr < 2; ++rr) {
            int slot = rr * 512 + tid;
            int row = slot >> 3, cl = slot & 7;
            int c = cl ^ (row & 7);
            const f16* src = feats1h + (size_t)nbr[row * 8 + tp] * 64 + c * 8;
            GLOAD_LDS16(src, &xs[buf][0] + (size_t)(rr * 512 + (tid & ~63)) * 8);
        }
    };
    auto STAGEW = [&](int tp, int buf) {
        int row = tid >> 3, cl = tid & 7;
        int c = cl ^ (row & 7);
        const f16* src = wdn + (size_t)((tp * 64 + row) * 64 + c * 8);
        GLOAD_LDS16(src, &wl[buf][0] + (size_t)(tid & ~63) * 8);
    };
    const int lane = tid & 63, wid = tid >> 6;
    const int l16 = lane & 15, lq = lane >> 4;
    const int wm = wid >> 1, wn = wid & 1;
    const int m0 = wm * 32, n0 = wn * 32;
    f32x4 acc[2][2] = {};
    STAGEX(0, 0);
    STAGEW(0, 0);
    STAGEX(1, 1);
    STAGEW(1, 1);
    for (int tp = 0; tp < 8; ++tp) {
        if (tp < 7) {
            asm volatile("s_waitcnt vmcnt(3)" ::: "memory");
        } else {
            asm volatile("s_waitcnt vmcnt(0)" ::: "memory");
        }
        __builtin_amdgcn_sched_barrier(0);
        __builtin_amdgcn_s_barrier();
        const f16* xbp = &xs[tp & 1][0];
        const f16* wbp = &wl[tp & 1][0];
        f16x8 a[2][2], bfr[2][2];
#pragma unroll
        for (int mi = 0; mi < 2; ++mi) {
            int row = m0 + mi * 16 + l16;
#pragma unroll
            for (int ks = 0; ks < 2; ++ks) {
                int ch = ks * 4 + lq;
                a[mi][ks] = *(const f16x8*)(xbp + (size_t)row * 64 + (ch ^ (row & 7)) * 8);
            }
        }
#pragma unroll
        for (int ni = 0; ni < 2; ++ni) {
            int col = n0 + ni * 16 + l16;
#pragma unroll
            for (int ks = 0; ks < 2; ++ks) {
                int ch = ks * 4 + lq;
                bfr[ni][ks] = *(const f16x8*)(wbp + (size_t)col * 64 + (ch ^ (col & 7)) * 8);
            }
        }
#pragma unroll
        for (int mi = 0; mi < 2; ++mi)
#pragma unroll
            for (int ni = 0; ni < 2; ++ni)
#pragma unroll
                for (int ks = 0; ks < 2; ++ks)
                    acc[mi][ni] = __builtin_amdgcn_mfma_f32_16x16x32_f16(a[mi][ks], bfr[ni][ks],
                                                                         acc[mi][ni], 0, 0, 0);
        asm volatile("s_waitcnt lgkmcnt(0)" ::: "memory");
        __builtin_amdgcn_sched_barrier(0);
        __builtin_amdgcn_s_barrier();
        if (tp + 2 < 8) {
            STAGEX(tp + 2, tp & 1);
            STAGEW(tp + 2, tp & 1);
        }
    }
#pragma unroll
    for (int mi = 0; mi < 2; ++mi) {
        int m = m0 + mi * 16 + lq * 4;
        int site = s0 + m;
        unsigned mword = *(const unsigned*)(mask + site);
#pragma unroll
        for (int ni = 0; ni < 2; ++ni) {
            int col = n0 + ni * 16 + l16;
            float bv = bias[col];
#pragma unroll
            for (int j = 0; j < 4; ++j) {
                float v = 0.f;
                if ((mword >> (8 * j)) & 255) {
                    v = acc[mi][ni][j] + bv;
                    v = v > 0.f ? v : 0.f;
                }
                out[(size_t)(site + j) * 64 + col] = (f16)v;
            }
        }
    }
}

// ---------------------------------------------------------------------------
// Generic dense 32^3 masked conv (27 taps), f16 MFMA. Halo staged once in LDS;
// W double-buffered via counted-vmcnt pipeline.
template <int CIN, int COUT, int NW, int RELUFROM>
__global__ __launch_bounds__(512) void dconv_kernel(const f16* __restrict__ x,
                                                    const f16* __restrict__ wp,  // 27 x COUT x CIN
                                                    const float* __restrict__ bias,
                                                    const unsigned char* __restrict__ mask,
                                                    const f16* __restrict__ zrow,
                                                    f16* __restrict__ out, int ostr) {
    constexpr int NCH = CIN / 8;          // 16B chunks per row
    constexpr int PSLOT = 34 * NCH;       // slots per pencil (k = -1..32)
    constexpr int STOT = 18 * PSLOT;      // total halo slots
    constexpr int RNDS = (STOT + 511) / 512;
    constexpr int MW = 8 / NW;
    constexpr int WM = 128 / MW, WN = COUT / NW;
    constexpr int FM = WM / 16, FN = WN / 16, KS = CIN / 32;
    constexpr int WSLOTS = COUT * NCH;  // real W slots per tap (<=512)
    __shared__ f16 xs[RNDS * 512 * 8];
    __shared__ f16 wl[2][512 * 8];

    const int tid = threadIdx.x;
    const int bid = blockIdx.x;
    const int i0 = bid >> 3, j0 = (bid & 7) * 4;

    // stage halo: 18 pencils x 34 rows (pad rows & OOB pencils <- zrow)
    for (int rr = 0; rr < RNDS; ++rr) {
        int slot = rr * 512 + tid;
        int p = slot / PSLOT;
        int rem = slot - p * PSLOT;
        int r = rem / NCH;
        int cl = rem - r * NCH;
        int c = cl ^ (r & (NCH - 1));
        int gi = i0 + p / 6 - 1, gj = j0 + p % 6 - 1, gk = r - 1;
        bool ok = (slot < STOT) && ((unsigned)gi < 32u) && ((unsigned)gj < 32u) &&
                  ((unsigned)gk < 32u);
        const f16* src = ok ? (x + (size_t)(((gi * 32 + gj) * 32 + gk) * CIN + c * 8)) : zrow;
        f16* dst = xs + (size_t)(rr * 512 + (tid & ~63)) * 8;
        GLOAD_LDS16(src, dst);
    }
    // W stage: 1 inst/thread
    auto STAGEW = [&](int tap, int buf) {
        int row = tid / NCH, cl = tid % NCH;
        int c = cl ^ (row & (NCH - 1));
        const f16* src = (tid < WSLOTS) ? (wp + (size_t)((tap * COUT + row) * CIN + c * 8)) : wp;
        GLOAD_LDS16(src, &wl[buf][0] + (size_t)(tid & ~63) * 8);
    };
    STAGEW(0, 0);
    STAGEW(1, 1);

    const int lane = tid & 63, wid = tid >> 6;
    const int l16 = lane & 15, lq = lane >> 4;
    const int wm = wid / NW, wn = wid - wm * NW;
    const int m0 = wm * WM, n0 = wn * WN;

    f32x4 acc[FM][FN] = {};

    for (int tap = 0; tap < 27; ++tap) {
        // wait halo + W(tap); W(tap+1)'s single inst stays in flight
        if (tap < 26) {
            asm volatile("s_waitcnt vmcnt(1)" ::: "memory");
        } else {
            asm volatile("s_waitcnt vmcnt(0)" ::: "memory");
        }
        __builtin_amdgcn_sched_barrier(0);
        __builtin_amdgcn_s_barrier();

        int di = tap / 9 - 1, dj = (tap / 3) % 3 - 1, dk = tap % 3 - 1;
        const f16* wbp = &wl[tap & 1][0];
        f16x8 a[FM][KS], bfr[FN][KS];
#pragma unroll
        for (int mi = 0; mi < FM; ++mi) {
            int m = m0 + mi * 16 + l16;
            int pj = m >> 5, k = m & 31;
            int p = (di + 1) * 6 + (pj + dj + 1);
            int r = k + dk + 1;
#pragma unroll
            for (int ks = 0; ks < KS; ++ks) {
                int ch = ks * 4 + lq;
                a[mi][ks] =
                    *(const f16x8*)(xs + (size_t)(p * PSLOT + r * NCH + (ch ^ (r & (NCH - 1)))) * 8);
            }
        }
#pragma unroll
        for (int ni = 0; ni < FN; ++ni) {
            int col = n0 + ni * 16 + l16;
#pragma unroll
            for (int ks = 0; ks < KS; ++ks) {
                int ch = ks * 4 + lq;
                bfr[ni][ks] =
                    *(const f16x8*)(wbp + (size_t)(col * NCH + (ch ^ (col & (NCH - 1)))) * 8);
            }
        }
#pragma unroll
        for (int mi = 0; mi < FM; ++mi)
#pragma unroll
            for (int ni = 0; ni < FN; ++ni)
#pragma unroll
                for (int ks = 0; ks < KS; ++ks)
                    acc[mi][ni] = __builtin_amdgcn_mfma_f32_16x16x32_f16(a[mi][ks], bfr[ni][ks],
                                                                         acc[mi][ni], 0, 0, 0);
        asm volatile("s_waitcnt lgkmcnt(0)" ::: "memory");
        __builtin_amdgcn_sched_barrier(0);
        __builtin_amdgcn_s_barrier();
        if (tap + 2 < 27) STAGEW(tap + 2, tap & 1);
    }

#pragma unroll
    for (int mi = 0; mi < FM; ++mi) {
        int m = m0 + mi * 16 + lq * 4;
        int pj = m >> 5, k = m & 31;
        int gsite = ((i0 * 32) + (j0 + pj)) * 32 + k;
        unsigned mword = *(const unsigned*)(mask + gsite);
#pragma unroll
        for (int ni = 0; ni < FN; ++ni) {
            int col = n0 + ni * 16 + l16;
            float bv = bias[col];
#pragma unroll
            for (int j = 0; j < 4; ++j) {
                float v = 0.f;
                if ((mword >> (8 * j)) & 255) {
                    v = acc[mi][ni][j] + bv;
                    if (col >= RELUFROM) v = v > 0.f ? v : 0.f;
                }
                out[(size_t)(gsite + j) * ostr + col] = (f16)v;
            }
        }
    }
}

// ---------------------------------------------------------------------------
// tail: p1 = (u1 . w12 + b12)*mask; y = [p0 + x_lo | p1 + x_hi].
template <typename OUTT>
__global__ __launch_bounds__(256) void tail_kernel(const f16* __restrict__ ph,   // 32768 x 64(48)
                                                   const f16* __restrict__ xh,   // 32768 x 64
                                                   const f16* __restrict__ w12,  // 32 x 16
                                                   const float* __restrict__ b12,
                                                   const unsigned char* __restrict__ mask,
                                                   OUTT* __restrict__ y /* 32768 x 64 */) {
    __shared__ float ws[512];
    __shared__ float bs[32];
    int tid = threadIdx.x;
    ws[tid] = (float)w12[tid];
    ws[tid + 256] = (float)w12[tid + 256];
    if (tid < 32) bs[tid] = b12[tid];
    __syncthreads();
    int g = tid >> 6, lane = tid & 63;
    int site = blockIdx.x * 64 + lane;
    const f16x8* pr = (const f16x8*)(ph + (size_t)site * 64);
    const f16x8* xr = (const f16x8*)(xh + (size_t)site * 64);
    float yv[16];
    int col0;
    if (g < 2) {
        col0 = g * 16;
        f16x8 p0 = pr[g * 2], p1 = pr[g * 2 + 1];
        f16x8 x0 = xr[g * 2], x1 = xr[g * 2 + 1];
#pragma unroll
        for (int j = 0; j < 8; ++j) {
            yv[j] = (float)p0[j] + (float)x0[j];
            yv[8 + j] = (float)p1[j] + (float)x1[j];
        }
    } else {
        int oc0 = (g - 2) * 16;
        col0 = 32 + oc0;
        f16x8 u0 = pr[4], u1 = pr[5];
        float u[16];
#pragma unroll
        for (int j = 0; j < 8; ++j) {
            u[j] = (float)u0[j];
            u[8 + j] = (float)u1[j];
        }
        f16x8 x0 = xr[4 + (g - 2) * 2], x1 = xr[5 + (g - 2) * 2];
        bool mk = mask[site] != 0;
#pragma unroll
        for (int oc = 0; oc < 16; ++oc) {
            float s = 0.f;
#pragma unroll
            for (int ic = 0; ic < 16; ++ic) s += u[ic] * ws[(oc0 + oc) * 16 + ic];
            float p1v = mk ? (s + bs[oc0 + oc]) : 0.f;
            yv[oc] = p1v + (float)((oc < 8) ? x0[oc] : x1[oc - 8]);
        }
    }
#pragma unroll
    for (int j = 0; j < 16; ++j) y[(size_t)site * 64 + col0 + j] = (OUTT)yv[j];
}

// final gather: out[m][oc] = xF[ds_site(m)][oc]
__global__ __launch_bounds__(256) void gather_kernel(const float* __restrict__ x,
                                                     const int* __restrict__ coords_ds, int M,
                                                     float* __restrict__ out) {
    int i = blockIdx.x * 256 + threadIdx.x;
    if (i < M * 64) {
        int m = i >> 6, oc = i & 63;
        int a = coords_ds[m * 3], b = coords_ds[m * 3 + 1], c = coords_ds[m * 3 + 2];
        out[i] = x[((size_t)((a * GDS + b) * GDS + c) << 6) + oc];
    }
}

// ---------------------------------------------------------------------------
extern "C" void kernel_launch(void* const* d_in, const int* in_sizes, int n_in,
                              void* d_out, int out_size, void* d_ws, size_t ws_size,
                              hipStream_t stream) {
    const int* coords = (const int*)d_in[0];
    const int* coords_ds = (const int*)d_in[1];
    const float* fc1 = (const float*)d_in[2];
    const float* fref = (const float*)d_in[3];
    const float* w_fuse = (const float*)d_in[4];
    const float* b_fuse = (const float*)d_in[5];
    const float* w_down = (const float*)d_in[6];
    const float* b_down = (const float*)d_in[7];
    const float* w_conv2 = (const float*)d_in[8];
    const float* b_conv2 = (const float*)d_in[9];
    const float* w_p00 = (const float*)d_in[10];
    const float* b_p00 = (const float*)d_in[11];
    const float* w_p01 = (const float*)d_in[12];
    const float* b_p01 = (const float*)d_in[13];
    const float* w_p10 = (const float*)d_in[14];
    const float* b_p10 = (const float*)d_in[15];
    const float* w_p11 = (const float*)d_in[16];
    const float* b_p11 = (const float*)d_in[17];
    const float* w_p12 = (const float*)d_in[18];
    const float* b_p12 = (const float*)d_in[19];

    const int N = in_sizes[0] / 3;
    const int M = in_sizes[1] / 3;
    const int L = in_sizes[10] / (27 * 64 * 16);
    const int NSITES = GDS * GDS * GDS;  // 32768

    size_t off = 0;
    auto alloc = [&](size_t bytes) {
        void* p = (char*)d_ws + off;
        off += (bytes + 255) & ~(size_t)255;
        return p;
    };
    int* idx_grid = (int*)alloc((size_t)GD * GD * GD * 4);
    unsigned char* ds_mask = (unsigned char*)alloc(NSITES);
    f16* zrow = (f16*)alloc(256);
    int* chunk_cnt = (int*)alloc(1024 * 4);
    int* chunk_off = (int*)alloc(1024 * 4);
    int* sites = (int*)alloc((size_t)N * 4);
    int* perm = (int*)alloc((size_t)N * 4);
    f16* featsB = (f16*)alloc((size_t)(N + 1) * 128 * 2);
    f16* feats1h = (f16*)alloc((size_t)(N + 1) * 64 * 2);
    f16* xdown = (f16*)alloc((size_t)NSITES * 64 * 2);
    f16* x0 = (f16*)alloc((size_t)NSITES * 64 * 2);
    f16* y1 = (f16*)alloc((size_t)NSITES * 64 * 2);
    f16* y2 = (f16*)alloc((size_t)NSITES * 64 * 2);
    f16* thh = (f16*)alloc((size_t)NSITES * 32 * 2);
    f16* ph = (f16*)alloc((size_t)NSITES * 64 * 2);  // stride 64, 48 used
    float* xF = (float*)alloc((size_t)NSITES * 64 * 4);
    f16* wc1 = (f16*)alloc((size_t)27 * 8192 * 2);
    f16* wdnh = (f16*)alloc((size_t)8 * 4096 * 2);
    f16* wc2h = (f16*)alloc((size_t)27 * 4096 * 2);
    f16* wfA = (f16*)alloc((size_t)L * 27 * 2048 * 2);
    f16* wfB = (f16*)alloc((size_t)L * 27 * 1536 * 2);
    f16* w12h = (f16*)alloc((size_t)L * 512 * 2);
    float* bA = (float*)alloc((size_t)L * 32 * 4);
    float* bB = (float*)alloc((size_t)L * 48 * 4);
    (void)ws_size;

    float* out = (float*)d_out;
    (void)out_size;
    (void)n_in;

    {
        int tot = 27 * 8192 + 8 * 4096 + 27 * 4096 + L * 27 * 2048 + L * 27 * 1536 + L * 512 +
                  L * 32 + L * 48;
        if (tot < GD * GD * GD) tot = GD * GD * GD;
        init_pack_kernel<<<(tot + 255) / 256, 256, 0, stream>>>(
            idx_grid, ds_mask, zrow, feats1h + (size_t)N * 64, w_fuse, w_down, w_conv2, w_p00,
            w_p01, w_p10, w_p11, w_p12, b_p00, b_p01, b_p10, b_p11, L, wc1, wdnh, wc2h, wfA, wfB,
            w12h, bA, bB);
    }
    {
        int mx = N > M ? N : M;
        scatter_kernel<<<(mx + 255) / 256, 256, 0, stream>>>(coords, N, coords_ds, M, idx_grid,
                                                             ds_mask);
    }
    // spatial sort of points (compaction over idx_grid)
    count_kernel<<<1024, 256, 0, stream>>>(idx_grid, chunk_cnt);
    prefix_kernel<<<1, 1024, 0, stream>>>(chunk_cnt, chunk_off);
    emit_kernel<<<1024, 256, 0, stream>>>(idx_grid, chunk_off, sites, perm);
    fusef_kernel<<<((N + 1) * 128 + 255) / 256, 256, 0, stream>>>(fc1, fref, perm, N, featsB);

    conv1_pipe<<<(N + 63) / 64, 512, 0, stream>>>(sites, idx_grid, N, featsB, wc1, b_fuse,
                                                  feats1h);
    down_mfma<<<NSITES / 128, 512, 0, stream>>>(feats1h, N, idx_grid, wdnh, b_down, ds_mask,
                                                xdown);
    dconv_kernel<64, 64, 2, 64>
        <<<256, 512, 0, stream>>>(xdown, wc2h, b_conv2, ds_mask, zrow, x0, 64);

    f16* x = x0;
    for (int l = 0; l < L; ++l) {
        dconv_kernel<64, 32, 2, 0>
            <<<256, 512, 0, stream>>>(x, wfA + (size_t)l * 27 * 2048, bA + l * 32, ds_mask, zrow,
                                      thh, 32);
        dconv_kernel<32, 48, 1, 32>
            <<<256, 512, 0, stream>>>(thh, wfB + (size_t)l * 27 * 1536, bB + l * 48, ds_mask, zrow,
                                      ph, 64);
        if (l < L - 1) {
            f16* yn = (l == 0) ? y1 : y2;
            tail_kernel<f16><<<NSITES / 64, 256, 0, stream>>>(ph, x, w12h + (size_t)l * 512,
                                                              b_p12 + l * 32, ds_mask, yn);
            x = yn;
        } else {
            tail_kernel<float><<<NSITES / 64, 256, 0, stream>>>(ph, x, w12h + (size_t)l * 512,
                                                                b_p12 + l * 32, ds_mask, xF);
        }
    }

    gather_kernel<<<(M * 64 + 255) / 256, 256, 0, stream>>>(xF, coords_ds, M, out);
}